// Round 1
// baseline (1028.190 us; speedup 1.0000x reference)
//
#include <hip/hip_runtime.h>
#include <hip/hip_bf16.h>
#include <cstdint>

// ---------------------------------------------------------------------------
// EpilepsyGNN: 3-layer GAT (4 heads x 32 -> 4x32 -> 1x32), BN(eval)+ReLU
// Strategy: build CSR by dst once, wave-per-node softmax-aggregate, no atomics
// in the float path. f32 everywhere for this round.
// ---------------------------------------------------------------------------

#define N_NODES 50000

__device__ __forceinline__ float lrelu02(float x) {
  return x > 0.f ? x : 0.2f * x;
}

// --- edge dtype detection: int64 (little-endian) has all-odd words == 0 -----
__global__ void detect_kernel(const unsigned* __restrict__ ei, int* __restrict__ flag) {
  int is64 = 1;
  for (int i = 1; i < 128; i += 2) {
    if (ei[i] != 0u) { is64 = 0; break; }
  }
  *flag = is64;
}

// --- convert edge_index -> int32 src/dst (+self loops), histogram degrees ---
__global__ void convert_kernel(const void* __restrict__ ei, int E, int Etot,
                               const int* __restrict__ flag,
                               int* __restrict__ src32, int* __restrict__ dst32,
                               int* __restrict__ deg) {
  int e = blockIdx.x * blockDim.x + threadIdx.x;
  if (e >= Etot) return;
  int s, d;
  if (e < E) {
    if (*flag) {
      const long long* p = (const long long*)ei;
      s = (int)p[e];
      d = (int)p[(size_t)E + e];
    } else {
      const int* p = (const int*)ei;
      s = p[e];
      d = p[E + e];
    }
  } else {  // self loop
    s = d = e - E;
  }
  src32[e] = s;
  dst32[e] = d;
  atomicAdd(&deg[d], 1);
}

// --- single-block exclusive scan of degrees -> row_ptr, cursor --------------
__global__ void scan_kernel(const int* __restrict__ deg, int* __restrict__ row_ptr,
                            int* __restrict__ cursor, int n) {
  __shared__ int sums[1024];
  int tid = threadIdx.x;
  int chunk = (n + 1023) / 1024;
  int lo = tid * chunk;
  int hi = lo + chunk; if (hi > n) hi = n;
  if (lo > n) lo = n;
  int s = 0;
  for (int i = lo; i < hi; ++i) s += deg[i];
  sums[tid] = s;
  __syncthreads();
  for (int off = 1; off < 1024; off <<= 1) {
    int v = (tid >= off) ? sums[tid - off] : 0;
    __syncthreads();
    sums[tid] += v;
    __syncthreads();
  }
  int run = (tid == 0) ? 0 : sums[tid - 1];
  for (int i = lo; i < hi; ++i) {
    row_ptr[i] = run;
    cursor[i] = run;
    run += deg[i];
  }
  if (tid == 1023) row_ptr[n] = sums[1023];
}

// --- scatter edges into CSR (order within a node irrelevant) ----------------
__global__ void scatter_kernel(const int* __restrict__ src32, const int* __restrict__ dst32,
                               int* __restrict__ cursor, int* __restrict__ csr_src, int Etot) {
  int e = blockIdx.x * blockDim.x + threadIdx.x;
  if (e >= Etot) return;
  int d = dst32[e];
  int pos = atomicAdd(&cursor[d], 1);
  csr_src[pos] = src32[e];
}

// --- transpose W[k][c] -> Wt[c][k] (K=128 fixed) ----------------------------
__global__ void transpose_kernel(const float* __restrict__ W, float* __restrict__ Wt, int OUTC) {
  int idx = blockIdx.x * blockDim.x + threadIdx.x;
  if (idx >= 128 * OUTC) return;
  int k = idx / OUTC;
  int c = idx % OUTC;
  Wt[c * 128 + k] = W[idx];
}

// --- simple f32 GEMM: A[n,128] @ W[128,OUTC] -> H[n,OUTC], Wt pretransposed -
template <int OUTC>
__global__ __launch_bounds__(256) void gemm_kernel(const float* __restrict__ A,
                                                   const float* __restrict__ Wt,
                                                   float* __restrict__ Hout, int n) {
  constexpr int CG = OUTC / 4;    // col groups per block
  constexpr int RG = 256 / CG;    // row groups per block
  constexpr int ROWS = RG * 4;
  int cg = threadIdx.x % CG;
  int rg = threadIdx.x / CG;
  int r0 = blockIdx.x * ROWS + rg * 4;
  int c0 = cg * 4;
  bool val[4];
#pragma unroll
  for (int i = 0; i < 4; ++i) val[i] = (r0 + i) < n;
  float acc[4][4];
#pragma unroll
  for (int i = 0; i < 4; ++i)
#pragma unroll
    for (int j = 0; j < 4; ++j) acc[i][j] = 0.f;

  for (int k4 = 0; k4 < 32; ++k4) {
    float4 xv[4], wv[4];
#pragma unroll
    for (int i = 0; i < 4; ++i) {
      if (val[i])
        xv[i] = *(const float4*)(A + (size_t)(r0 + i) * 128 + k4 * 4);
      else
        xv[i] = make_float4(0.f, 0.f, 0.f, 0.f);
    }
#pragma unroll
    for (int j = 0; j < 4; ++j)
      wv[j] = *(const float4*)(Wt + (size_t)(c0 + j) * 128 + k4 * 4);
#pragma unroll
    for (int i = 0; i < 4; ++i)
#pragma unroll
      for (int j = 0; j < 4; ++j) {
        acc[i][j] = fmaf(xv[i].x, wv[j].x, acc[i][j]);
        acc[i][j] = fmaf(xv[i].y, wv[j].y, acc[i][j]);
        acc[i][j] = fmaf(xv[i].z, wv[j].z, acc[i][j]);
        acc[i][j] = fmaf(xv[i].w, wv[j].w, acc[i][j]);
      }
  }
#pragma unroll
  for (int i = 0; i < 4; ++i) {
    if (!val[i]) continue;
    float4 o = make_float4(acc[i][0], acc[i][1], acc[i][2], acc[i][3]);
    *(float4*)(Hout + (size_t)(r0 + i) * OUTC + c0) = o;
  }
}

// --- attention logits: al[n,h] = sum_c h[n,h,c] * a[h,c] --------------------
template <int H, int C>
__global__ void al_kernel(const float* __restrict__ h, const float* __restrict__ a_s,
                          const float* __restrict__ a_d, float* __restrict__ alS,
                          float* __restrict__ alD, int n) {
  int idx = blockIdx.x * blockDim.x + threadIdx.x;
  if (idx >= n * H) return;
  int head = idx % H;
  const float* hp = h + (size_t)idx * C;  // layout [n,H,C]: idx = node*H+head
  const float* sp = a_s + head * C;
  const float* dp = a_d + head * C;
  float s = 0.f, d = 0.f;
#pragma unroll
  for (int i = 0; i < C; i += 4) {
    float4 hv = *(const float4*)(hp + i);
    float4 sv = *(const float4*)(sp + i);
    float4 dv = *(const float4*)(dp + i);
    s = fmaf(hv.x, sv.x, s); s = fmaf(hv.y, sv.y, s);
    s = fmaf(hv.z, sv.z, s); s = fmaf(hv.w, sv.w, s);
    d = fmaf(hv.x, dv.x, d); d = fmaf(hv.y, dv.y, d);
    d = fmaf(hv.z, dv.z, d); d = fmaf(hv.w, dv.w, d);
  }
  alS[idx] = s;
  alD[idx] = d;
}

// --- wave-per-node softmax + aggregate + (bias, BN, ReLU) epilogue ----------
template <int H, int C, bool BN>
__global__ __launch_bounds__(256) void agg_kernel(
    const int* __restrict__ row_ptr, const int* __restrict__ csr_src,
    const float* __restrict__ alS, const float* __restrict__ alD,
    const float* __restrict__ hfeat, const float* __restrict__ bias,
    const float* __restrict__ bnw, const float* __restrict__ bnb,
    const float* __restrict__ bnm, const float* __restrict__ bnv,
    float* __restrict__ out, int n) {
  constexpr int HC = H * C;
  int lane = threadIdx.x & 63;
  int v = (blockIdx.x * blockDim.x + threadIdx.x) >> 6;
  if (v >= n) return;
  int rs = row_ptr[v];
  int re = row_ptr[v + 1];

  if constexpr (HC == 128) {
    int c0 = lane, c1 = lane + 64;
    int h0 = lane >> 5;        // head of c0 (0..1)
    int h1 = 2 + (lane >> 5);  // head of c1 (2..3)
    float ad0 = alD[v * H + h0];
    float ad1 = alD[v * H + h1];
    float m0 = -1e30f, m1 = -1e30f;
    for (int e = rs; e < re; ++e) {
      int s = csr_src[e];
      float x0 = lrelu02(alS[s * H + h0] + ad0);
      float x1 = lrelu02(alS[s * H + h1] + ad1);
      m0 = fmaxf(m0, x0);
      m1 = fmaxf(m1, x1);
    }
    float acc0 = 0.f, acc1 = 0.f, d0 = 0.f, d1 = 0.f;
    for (int e = rs; e < re; ++e) {
      int s = csr_src[e];
      float x0 = lrelu02(alS[s * H + h0] + ad0);
      float x1 = lrelu02(alS[s * H + h1] + ad1);
      float w0 = __expf(x0 - m0);
      float w1 = __expf(x1 - m1);
      d0 += w0;
      d1 += w1;
      const float* hp = hfeat + (size_t)s * HC;
      acc0 = fmaf(w0, hp[c0], acc0);
      acc1 = fmaf(w1, hp[c1], acc1);
    }
    float g0 = acc0 / (d0 + 1e-16f) + bias[c0];
    float g1 = acc1 / (d1 + 1e-16f) + bias[c1];
    if constexpr (BN) {
      g0 = (g0 - bnm[c0]) * (bnw[c0] * rsqrtf(bnv[c0] + 1e-5f)) + bnb[c0];
      g1 = (g1 - bnm[c1]) * (bnw[c1] * rsqrtf(bnv[c1] + 1e-5f)) + bnb[c1];
      g0 = fmaxf(g0, 0.f);
      g1 = fmaxf(g1, 0.f);
    }
    out[(size_t)v * HC + c0] = g0;
    out[(size_t)v * HC + c1] = g1;
  } else {  // HC == 32, H == 1
    int c = lane & 31;
    float ad = alD[v];
    float m = -1e30f;
    for (int e = rs; e < re; ++e) {
      int s = csr_src[e];
      float x = lrelu02(alS[s] + ad);
      m = fmaxf(m, x);
    }
    float acc = 0.f, den = 0.f;
    for (int e = rs; e < re; ++e) {
      int s = csr_src[e];
      float x = lrelu02(alS[s] + ad);
      float w = __expf(x - m);
      den += w;
      acc = fmaf(w, hfeat[(size_t)s * 32 + c], acc);
    }
    if (lane < 32) out[(size_t)v * 32 + c] = acc / (den + 1e-16f) + bias[c];
  }
}

// ---------------------------------------------------------------------------
extern "C" void kernel_launch(void* const* d_in, const int* in_sizes, int n_in,
                              void* d_out, int out_size, void* d_ws, size_t ws_size,
                              hipStream_t stream) {
  const float* x = (const float*)d_in[0];
  const void* ei = d_in[1];
  const float* w1 = (const float*)d_in[2];
  const float* as1 = (const float*)d_in[3];
  const float* ad1 = (const float*)d_in[4];
  const float* b1 = (const float*)d_in[5];
  const float* bn1w = (const float*)d_in[6];
  const float* bn1b = (const float*)d_in[7];
  const float* bn1m = (const float*)d_in[8];
  const float* bn1v = (const float*)d_in[9];
  const float* w2 = (const float*)d_in[10];
  const float* as2 = (const float*)d_in[11];
  const float* ad2 = (const float*)d_in[12];
  const float* b2 = (const float*)d_in[13];
  const float* bn2w = (const float*)d_in[14];
  const float* bn2b = (const float*)d_in[15];
  const float* bn2m = (const float*)d_in[16];
  const float* bn2v = (const float*)d_in[17];
  const float* w3 = (const float*)d_in[18];
  const float* as3 = (const float*)d_in[19];
  const float* ad3 = (const float*)d_in[20];
  const float* b3 = (const float*)d_in[21];

  const int N = in_sizes[0] / 128;
  const int E = in_sizes[1] / 2;
  const int Etot = E + N;

  // workspace layout (256B aligned slices)
  char* base = (char*)d_ws;
  size_t off = 0;
  auto alloc = [&](size_t bytes) {
    void* p = base + off;
    off = (off + bytes + 255) & ~(size_t)255;
    return p;
  };
  int* flag = (int*)alloc(4);
  int* src32 = (int*)alloc((size_t)Etot * 4);
  int* dst32 = (int*)alloc((size_t)Etot * 4);
  int* deg = (int*)alloc((size_t)N * 4);
  int* row_ptr = (int*)alloc((size_t)(N + 1) * 4);
  int* cursor = (int*)alloc((size_t)N * 4);
  int* csr_src = (int*)alloc((size_t)Etot * 4);
  float* hbuf = (float*)alloc((size_t)N * 128 * 4);
  float* gbuf = (float*)alloc((size_t)N * 128 * 4);
  float* alS = (float*)alloc((size_t)N * 4 * 4);
  float* alD = (float*)alloc((size_t)N * 4 * 4);
  float* Wt = (float*)alloc((size_t)128 * 128 * 4);
  (void)ws_size;

  hipMemsetAsync(deg, 0, (size_t)N * 4, stream);

  detect_kernel<<<1, 1, 0, stream>>>((const unsigned*)ei, flag);
  convert_kernel<<<(Etot + 255) / 256, 256, 0, stream>>>(ei, E, Etot, flag, src32, dst32, deg);
  scan_kernel<<<1, 1024, 0, stream>>>(deg, row_ptr, cursor, N);
  scatter_kernel<<<(Etot + 255) / 256, 256, 0, stream>>>(src32, dst32, cursor, csr_src, Etot);

  const int aggGrid = (N * 64 + 255) / 256;

  // ---- layer 1 ----
  transpose_kernel<<<(128 * 128 + 255) / 256, 256, 0, stream>>>(w1, Wt, 128);
  gemm_kernel<128><<<(N + 31) / 32, 256, 0, stream>>>(x, Wt, hbuf, N);
  al_kernel<4, 32><<<(N * 4 + 255) / 256, 256, 0, stream>>>(hbuf, as1, ad1, alS, alD, N);
  agg_kernel<4, 32, true><<<aggGrid, 256, 0, stream>>>(row_ptr, csr_src, alS, alD, hbuf,
                                                       b1, bn1w, bn1b, bn1m, bn1v, gbuf, N);
  // ---- layer 2 ----
  transpose_kernel<<<(128 * 128 + 255) / 256, 256, 0, stream>>>(w2, Wt, 128);
  gemm_kernel<128><<<(N + 31) / 32, 256, 0, stream>>>(gbuf, Wt, hbuf, N);
  al_kernel<4, 32><<<(N * 4 + 255) / 256, 256, 0, stream>>>(hbuf, as2, ad2, alS, alD, N);
  agg_kernel<4, 32, true><<<aggGrid, 256, 0, stream>>>(row_ptr, csr_src, alS, alD, hbuf,
                                                       b2, bn2w, bn2b, bn2m, bn2v, gbuf, N);
  // ---- layer 3 ----
  transpose_kernel<<<(128 * 32 + 255) / 256, 256, 0, stream>>>(w3, Wt, 32);
  gemm_kernel<32><<<(N + 127) / 128, 256, 0, stream>>>(gbuf, Wt, hbuf, N);
  al_kernel<1, 32><<<(N + 255) / 256, 256, 0, stream>>>(hbuf, as3, ad3, alS, alD, N);
  agg_kernel<1, 32, false><<<aggGrid, 256, 0, stream>>>(row_ptr, csr_src, alS, alD, hbuf,
                                                        b3, nullptr, nullptr, nullptr, nullptr,
                                                        (float*)d_out, N);
}

// Round 2
// 716.137 us; speedup vs baseline: 1.4357x; 1.4357x over previous
//
#include <hip/hip_runtime.h>
#include <hip/hip_bf16.h>
#include <cstdint>

// ---------------------------------------------------------------------------
// EpilepsyGNN: 3-layer GAT (4 heads x 32 -> 4x32 -> 1x32), BN(eval)+ReLU
// CSR by dst built once; agg = lane-parallel LDS staging + unrolled
// channel-parallel gather (latency-chain ~6 deep instead of ~34).
// ---------------------------------------------------------------------------

__device__ __forceinline__ float lrelu02(float x) {
  return x > 0.f ? x : 0.2f * x;
}

// --- edge dtype detection: int64 (little-endian) has all-odd words == 0 -----
__global__ void detect_kernel(const unsigned* __restrict__ ei, int* __restrict__ flag) {
  int is64 = 1;
  for (int i = 1; i < 128; i += 2) {
    if (ei[i] != 0u) { is64 = 0; break; }
  }
  *flag = is64;
}

// --- convert edge_index -> int32 src/dst (+self loops), histogram degrees ---
__global__ void convert_kernel(const void* __restrict__ ei, int E, int Etot,
                               const int* __restrict__ flag,
                               int* __restrict__ src32, int* __restrict__ dst32,
                               int* __restrict__ deg) {
  int e = blockIdx.x * blockDim.x + threadIdx.x;
  if (e >= Etot) return;
  int s, d;
  if (e < E) {
    if (*flag) {
      const long long* p = (const long long*)ei;
      s = (int)p[e];
      d = (int)p[(size_t)E + e];
    } else {
      const int* p = (const int*)ei;
      s = p[e];
      d = p[E + e];
    }
  } else {  // self loop
    s = d = e - E;
  }
  src32[e] = s;
  dst32[e] = d;
  atomicAdd(&deg[d], 1);
}

// --- single-block exclusive scan of degrees -> row_ptr, cursor --------------
__global__ void scan_kernel(const int* __restrict__ deg, int* __restrict__ row_ptr,
                            int* __restrict__ cursor, int n) {
  __shared__ int sums[1024];
  int tid = threadIdx.x;
  int chunk = (n + 1023) / 1024;
  int lo = tid * chunk;
  int hi = lo + chunk; if (hi > n) hi = n;
  if (lo > n) lo = n;
  int s = 0;
  for (int i = lo; i < hi; ++i) s += deg[i];
  sums[tid] = s;
  __syncthreads();
  for (int off = 1; off < 1024; off <<= 1) {
    int v = (tid >= off) ? sums[tid - off] : 0;
    __syncthreads();
    sums[tid] += v;
    __syncthreads();
  }
  int run = (tid == 0) ? 0 : sums[tid - 1];
  for (int i = lo; i < hi; ++i) {
    row_ptr[i] = run;
    cursor[i] = run;
    run += deg[i];
  }
  if (tid == 1023) row_ptr[n] = sums[1023];
}

// --- scatter edges into CSR (order within a node irrelevant) ----------------
__global__ void scatter_kernel(const int* __restrict__ src32, const int* __restrict__ dst32,
                               int* __restrict__ cursor, int* __restrict__ csr_src, int Etot) {
  int e = blockIdx.x * blockDim.x + threadIdx.x;
  if (e >= Etot) return;
  int d = dst32[e];
  int pos = atomicAdd(&cursor[d], 1);
  csr_src[pos] = src32[e];
}

// --- transpose W[k][c] -> Wt[c][k] (K=128 fixed) ----------------------------
__global__ void transpose_kernel(const float* __restrict__ W, float* __restrict__ Wt, int OUTC) {
  int idx = blockIdx.x * blockDim.x + threadIdx.x;
  if (idx >= 128 * OUTC) return;
  int k = idx / OUTC;
  int c = idx % OUTC;
  Wt[c * 128 + k] = W[idx];
}

// --- simple f32 GEMM: A[n,128] @ W[128,OUTC] -> H[n,OUTC], Wt pretransposed -
template <int OUTC>
__global__ __launch_bounds__(256) void gemm_kernel(const float* __restrict__ A,
                                                   const float* __restrict__ Wt,
                                                   float* __restrict__ Hout, int n) {
  constexpr int CG = OUTC / 4;    // col groups per block
  constexpr int RG = 256 / CG;    // row groups per block
  constexpr int ROWS = RG * 4;
  int cg = threadIdx.x % CG;
  int rg = threadIdx.x / CG;
  int r0 = blockIdx.x * ROWS + rg * 4;
  int c0 = cg * 4;
  bool val[4];
#pragma unroll
  for (int i = 0; i < 4; ++i) val[i] = (r0 + i) < n;
  float acc[4][4];
#pragma unroll
  for (int i = 0; i < 4; ++i)
#pragma unroll
    for (int j = 0; j < 4; ++j) acc[i][j] = 0.f;

  for (int k4 = 0; k4 < 32; ++k4) {
    float4 xv[4], wv[4];
#pragma unroll
    for (int i = 0; i < 4; ++i) {
      if (val[i])
        xv[i] = *(const float4*)(A + (size_t)(r0 + i) * 128 + k4 * 4);
      else
        xv[i] = make_float4(0.f, 0.f, 0.f, 0.f);
    }
#pragma unroll
    for (int j = 0; j < 4; ++j)
      wv[j] = *(const float4*)(Wt + (size_t)(c0 + j) * 128 + k4 * 4);
#pragma unroll
    for (int i = 0; i < 4; ++i)
#pragma unroll
      for (int j = 0; j < 4; ++j) {
        acc[i][j] = fmaf(xv[i].x, wv[j].x, acc[i][j]);
        acc[i][j] = fmaf(xv[i].y, wv[j].y, acc[i][j]);
        acc[i][j] = fmaf(xv[i].z, wv[j].z, acc[i][j]);
        acc[i][j] = fmaf(xv[i].w, wv[j].w, acc[i][j]);
      }
  }
#pragma unroll
  for (int i = 0; i < 4; ++i) {
    if (!val[i]) continue;
    float4 o = make_float4(acc[i][0], acc[i][1], acc[i][2], acc[i][3]);
    *(float4*)(Hout + (size_t)(r0 + i) * OUTC + c0) = o;
  }
}

// --- attention logits: al[n,h] = sum_c h[n,h,c] * a[h,c] --------------------
template <int H, int C>
__global__ void al_kernel(const float* __restrict__ h, const float* __restrict__ a_s,
                          const float* __restrict__ a_d, float* __restrict__ alS,
                          float* __restrict__ alD, int n) {
  int idx = blockIdx.x * blockDim.x + threadIdx.x;
  if (idx >= n * H) return;
  int head = idx % H;
  const float* hp = h + (size_t)idx * C;  // layout [n,H,C]: idx = node*H+head
  const float* sp = a_s + head * C;
  const float* dp = a_d + head * C;
  float s = 0.f, d = 0.f;
#pragma unroll
  for (int i = 0; i < C; i += 4) {
    float4 hv = *(const float4*)(hp + i);
    float4 sv = *(const float4*)(sp + i);
    float4 dv = *(const float4*)(dp + i);
    s = fmaf(hv.x, sv.x, s); s = fmaf(hv.y, sv.y, s);
    s = fmaf(hv.z, sv.z, s); s = fmaf(hv.w, sv.w, s);
    d = fmaf(hv.x, dv.x, d); d = fmaf(hv.y, dv.y, d);
    d = fmaf(hv.z, dv.z, d); d = fmaf(hv.w, dv.w, d);
  }
  alS[idx] = s;
  alD[idx] = d;
}

// --- agg: lane-parallel staging + unrolled channel-parallel gather ----------
// H=4,C=32: 64 lanes per node, lane handles channels 2sl,2sl+1 (head sl>>4).
// H=1,C=32: 32 lanes per node (2 nodes/wave), lane handles channel sl.
template <int H, int C, bool BN>
__global__ __launch_bounds__(256) void agg_kernel(
    const int* __restrict__ row_ptr, const int* __restrict__ csr_src,
    const float* __restrict__ alS, const float* __restrict__ alD,
    const float* __restrict__ hfeat, const float* __restrict__ bias,
    const float* __restrict__ bnw, const float* __restrict__ bnb,
    const float* __restrict__ bnm, const float* __restrict__ bnv,
    float* __restrict__ out, int n) {
  constexpr int HC = H * C;
  constexpr int LPN = (HC >= 128) ? 64 : 32;  // lanes per node
  constexpr int NPB = 256 / LPN;              // node slots per block
  constexpr int KCAP = 96;                    // staged-edge capacity

  __shared__ __align__(16) float sX[NPB][KCAP * H];
  __shared__ int sIdx[NPB][KCAP];

  const int slot = threadIdx.x / LPN;
  const int sl = threadIdx.x % LPN;
  const int v = blockIdx.x * NPB + slot;
  const bool active = v < n;

  int rs = 0, re = 0;
  if (active) { rs = row_ptr[v]; re = row_ptr[v + 1]; }
  const int deg = re - rs;
  const int degS = deg < KCAP ? deg : KCAP;

  float m[H];
#pragma unroll
  for (int h2 = 0; h2 < H; ++h2) m[h2] = -1e30f;

  if constexpr (H == 4) {
    float4 ad4 = make_float4(0.f, 0.f, 0.f, 0.f);
    if (active) ad4 = *(const float4*)(alD + (size_t)v * 4);
    for (int k = sl; k < degS; k += LPN) {
      int s = csr_src[rs + k];
      sIdx[slot][k] = s;
      float4 a4 = *(const float4*)(alS + (size_t)s * 4);
      float x0 = lrelu02(a4.x + ad4.x);
      float x1 = lrelu02(a4.y + ad4.y);
      float x2 = lrelu02(a4.z + ad4.z);
      float x3 = lrelu02(a4.w + ad4.w);
      ((float4*)&sX[slot][0])[k] = make_float4(x0, x1, x2, x3);
      m[0] = fmaxf(m[0], x0); m[1] = fmaxf(m[1], x1);
      m[2] = fmaxf(m[2], x2); m[3] = fmaxf(m[3], x3);
    }
    // overflow edges contribute to max only (recomputed later)
    for (int k = KCAP + sl; k < deg; k += LPN) {
      int s = csr_src[rs + k];
      float4 a4 = *(const float4*)(alS + (size_t)s * 4);
      m[0] = fmaxf(m[0], lrelu02(a4.x + ad4.x));
      m[1] = fmaxf(m[1], lrelu02(a4.y + ad4.y));
      m[2] = fmaxf(m[2], lrelu02(a4.z + ad4.z));
      m[3] = fmaxf(m[3], lrelu02(a4.w + ad4.w));
    }
#pragma unroll
    for (int h2 = 0; h2 < 4; ++h2) {
#pragma unroll
      for (int off = 32; off >= 1; off >>= 1)
        m[h2] = fmaxf(m[h2], __shfl_xor(m[h2], off));
    }
  } else {  // H == 1
    float ad = active ? alD[v] : 0.f;
    for (int k = sl; k < degS; k += LPN) {
      int s = csr_src[rs + k];
      sIdx[slot][k] = s;
      float x = lrelu02(alS[s] + ad);
      sX[slot][k] = x;
      m[0] = fmaxf(m[0], x);
    }
    for (int k = KCAP + sl; k < deg; k += LPN) {
      int s = csr_src[rs + k];
      m[0] = fmaxf(m[0], lrelu02(alS[s] + ad));
    }
#pragma unroll
    for (int off = 16; off >= 1; off >>= 1)
      m[0] = fmaxf(m[0], __shfl_xor(m[0], off));
  }

  __syncthreads();

  if constexpr (H == 4) {
    const int c = 2 * sl;          // channels c, c+1
    const int h = sl >> 4;         // head 0..3
    const float mh = (h == 0) ? m[0] : (h == 1) ? m[1] : (h == 2) ? m[2] : m[3];
    float2 acc = make_float2(0.f, 0.f);
    float den = 0.f;
    int j = 0;
    for (; j + 4 <= degS; j += 4) {
      int s0 = sIdx[slot][j + 0], s1 = sIdx[slot][j + 1];
      int s2 = sIdx[slot][j + 2], s3 = sIdx[slot][j + 3];
      float x0 = sX[slot][(j + 0) * 4 + h];
      float x1 = sX[slot][(j + 1) * 4 + h];
      float x2 = sX[slot][(j + 2) * 4 + h];
      float x3 = sX[slot][(j + 3) * 4 + h];
      float2 f0 = *(const float2*)(hfeat + (size_t)s0 * 128 + c);
      float2 f1 = *(const float2*)(hfeat + (size_t)s1 * 128 + c);
      float2 f2 = *(const float2*)(hfeat + (size_t)s2 * 128 + c);
      float2 f3 = *(const float2*)(hfeat + (size_t)s3 * 128 + c);
      float w0 = __expf(x0 - mh), w1 = __expf(x1 - mh);
      float w2 = __expf(x2 - mh), w3 = __expf(x3 - mh);
      den += (w0 + w1) + (w2 + w3);
      acc.x = fmaf(w0, f0.x, acc.x); acc.y = fmaf(w0, f0.y, acc.y);
      acc.x = fmaf(w1, f1.x, acc.x); acc.y = fmaf(w1, f1.y, acc.y);
      acc.x = fmaf(w2, f2.x, acc.x); acc.y = fmaf(w2, f2.y, acc.y);
      acc.x = fmaf(w3, f3.x, acc.x); acc.y = fmaf(w3, f3.y, acc.y);
    }
    for (; j < degS; ++j) {
      int s = sIdx[slot][j];
      float x = sX[slot][j * 4 + h];
      float2 f = *(const float2*)(hfeat + (size_t)s * 128 + c);
      float w = __expf(x - mh);
      den += w;
      acc.x = fmaf(w, f.x, acc.x); acc.y = fmaf(w, f.y, acc.y);
    }
    if (deg > KCAP) {  // cold fallback, recompute logits
      float adh = alD[(size_t)v * 4 + h];
      for (int e = rs + KCAP; e < re; ++e) {
        int s = csr_src[e];
        float x = lrelu02(alS[(size_t)s * 4 + h] + adh);
        float w = __expf(x - mh);
        den += w;
        float2 f = *(const float2*)(hfeat + (size_t)s * 128 + c);
        acc.x = fmaf(w, f.x, acc.x); acc.y = fmaf(w, f.y, acc.y);
      }
    }
    if (active) {
      float inv = 1.f / (den + 1e-16f);
      float2 b2v = *(const float2*)(bias + c);
      float g0 = acc.x * inv + b2v.x;
      float g1 = acc.y * inv + b2v.y;
      if constexpr (BN) {
        float2 bw = *(const float2*)(bnw + c);
        float2 bb = *(const float2*)(bnb + c);
        float2 bm = *(const float2*)(bnm + c);
        float2 bv = *(const float2*)(bnv + c);
        g0 = (g0 - bm.x) * (bw.x * rsqrtf(bv.x + 1e-5f)) + bb.x;
        g1 = (g1 - bm.y) * (bw.y * rsqrtf(bv.y + 1e-5f)) + bb.y;
        g0 = fmaxf(g0, 0.f);
        g1 = fmaxf(g1, 0.f);
      }
      *(float2*)(out + (size_t)v * 128 + c) = make_float2(g0, g1);
    }
  } else {  // H == 1, C == 32
    const int c = sl;
    const float mh = m[0];
    float acc = 0.f, den = 0.f;
    int j = 0;
    for (; j + 4 <= degS; j += 4) {
      int s0 = sIdx[slot][j + 0], s1 = sIdx[slot][j + 1];
      int s2 = sIdx[slot][j + 2], s3 = sIdx[slot][j + 3];
      float x0 = sX[slot][j + 0], x1 = sX[slot][j + 1];
      float x2 = sX[slot][j + 2], x3 = sX[slot][j + 3];
      float f0 = hfeat[(size_t)s0 * 32 + c];
      float f1 = hfeat[(size_t)s1 * 32 + c];
      float f2 = hfeat[(size_t)s2 * 32 + c];
      float f3 = hfeat[(size_t)s3 * 32 + c];
      float w0 = __expf(x0 - mh), w1 = __expf(x1 - mh);
      float w2 = __expf(x2 - mh), w3 = __expf(x3 - mh);
      den += (w0 + w1) + (w2 + w3);
      acc = fmaf(w0, f0, acc); acc = fmaf(w1, f1, acc);
      acc = fmaf(w2, f2, acc); acc = fmaf(w3, f3, acc);
    }
    for (; j < degS; ++j) {
      int s = sIdx[slot][j];
      float w = __expf(sX[slot][j] - mh);
      den += w;
      acc = fmaf(w, hfeat[(size_t)s * 32 + c], acc);
    }
    if (deg > KCAP) {
      float ad = alD[v];
      for (int e = rs + KCAP; e < re; ++e) {
        int s = csr_src[e];
        float w = __expf(lrelu02(alS[s] + ad) - mh);
        den += w;
        acc = fmaf(w, hfeat[(size_t)s * 32 + c], acc);
      }
    }
    if (active) {
      out[(size_t)v * 32 + c] = acc / (den + 1e-16f) + bias[c];
    }
  }
}

// ---------------------------------------------------------------------------
extern "C" void kernel_launch(void* const* d_in, const int* in_sizes, int n_in,
                              void* d_out, int out_size, void* d_ws, size_t ws_size,
                              hipStream_t stream) {
  const float* x = (const float*)d_in[0];
  const void* ei = d_in[1];
  const float* w1 = (const float*)d_in[2];
  const float* as1 = (const float*)d_in[3];
  const float* ad1 = (const float*)d_in[4];
  const float* b1 = (const float*)d_in[5];
  const float* bn1w = (const float*)d_in[6];
  const float* bn1b = (const float*)d_in[7];
  const float* bn1m = (const float*)d_in[8];
  const float* bn1v = (const float*)d_in[9];
  const float* w2 = (const float*)d_in[10];
  const float* as2 = (const float*)d_in[11];
  const float* ad2 = (const float*)d_in[12];
  const float* b2 = (const float*)d_in[13];
  const float* bn2w = (const float*)d_in[14];
  const float* bn2b = (const float*)d_in[15];
  const float* bn2m = (const float*)d_in[16];
  const float* bn2v = (const float*)d_in[17];
  const float* w3 = (const float*)d_in[18];
  const float* as3 = (const float*)d_in[19];
  const float* ad3 = (const float*)d_in[20];
  const float* b3 = (const float*)d_in[21];

  const int N = in_sizes[0] / 128;
  const int E = in_sizes[1] / 2;
  const int Etot = E + N;

  // workspace layout (256B aligned slices)
  char* base = (char*)d_ws;
  size_t off = 0;
  auto alloc = [&](size_t bytes) {
    void* p = base + off;
    off = (off + bytes + 255) & ~(size_t)255;
    return p;
  };
  int* flag = (int*)alloc(4);
  int* src32 = (int*)alloc((size_t)Etot * 4);
  int* dst32 = (int*)alloc((size_t)Etot * 4);
  int* deg = (int*)alloc((size_t)N * 4);
  int* row_ptr = (int*)alloc((size_t)(N + 1) * 4);
  int* cursor = (int*)alloc((size_t)N * 4);
  int* csr_src = (int*)alloc((size_t)Etot * 4);
  float* hbuf = (float*)alloc((size_t)N * 128 * 4);
  float* gbuf = (float*)alloc((size_t)N * 128 * 4);
  float* alS = (float*)alloc((size_t)N * 4 * 4);
  float* alD = (float*)alloc((size_t)N * 4 * 4);
  float* Wt = (float*)alloc((size_t)128 * 128 * 4);
  (void)ws_size;

  hipMemsetAsync(deg, 0, (size_t)N * 4, stream);

  detect_kernel<<<1, 1, 0, stream>>>((const unsigned*)ei, flag);
  convert_kernel<<<(Etot + 255) / 256, 256, 0, stream>>>(ei, E, Etot, flag, src32, dst32, deg);
  scan_kernel<<<1, 1024, 0, stream>>>(deg, row_ptr, cursor, N);
  scatter_kernel<<<(Etot + 255) / 256, 256, 0, stream>>>(src32, dst32, cursor, csr_src, Etot);

  // ---- layer 1 ----
  transpose_kernel<<<(128 * 128 + 255) / 256, 256, 0, stream>>>(w1, Wt, 128);
  gemm_kernel<128><<<(N + 31) / 32, 256, 0, stream>>>(x, Wt, hbuf, N);
  al_kernel<4, 32><<<(N * 4 + 255) / 256, 256, 0, stream>>>(hbuf, as1, ad1, alS, alD, N);
  agg_kernel<4, 32, true><<<(N + 3) / 4, 256, 0, stream>>>(row_ptr, csr_src, alS, alD, hbuf,
                                                           b1, bn1w, bn1b, bn1m, bn1v, gbuf, N);
  // ---- layer 2 ----
  transpose_kernel<<<(128 * 128 + 255) / 256, 256, 0, stream>>>(w2, Wt, 128);
  gemm_kernel<128><<<(N + 31) / 32, 256, 0, stream>>>(gbuf, Wt, hbuf, N);
  al_kernel<4, 32><<<(N * 4 + 255) / 256, 256, 0, stream>>>(hbuf, as2, ad2, alS, alD, N);
  agg_kernel<4, 32, true><<<(N + 3) / 4, 256, 0, stream>>>(row_ptr, csr_src, alS, alD, hbuf,
                                                           b2, bn2w, bn2b, bn2m, bn2v, gbuf, N);
  // ---- layer 3 ----
  transpose_kernel<<<(128 * 32 + 255) / 256, 256, 0, stream>>>(w3, Wt, 32);
  gemm_kernel<32><<<(N + 127) / 128, 256, 0, stream>>>(gbuf, Wt, hbuf, N);
  al_kernel<1, 32><<<(N + 255) / 256, 256, 0, stream>>>(hbuf, as3, ad3, alS, alD, N);
  agg_kernel<1, 32, false><<<(N + 7) / 8, 256, 0, stream>>>(row_ptr, csr_src, alS, alD, hbuf,
                                                            b3, nullptr, nullptr, nullptr, nullptr,
                                                            (float*)d_out, N);
}

// Round 3
// 461.916 us; speedup vs baseline: 2.2259x; 1.5504x over previous
//
#include <hip/hip_runtime.h>
#include <hip/hip_bf16.h>
#include <cstdint>

// ---------------------------------------------------------------------------
// EpilepsyGNN: 3-layer GAT (4 heads x 32 -> 4x32 -> 1x32), BN(eval)+ReLU
// CSR by dst built once; agg = lane-parallel LDS staging + unrolled
// channel-parallel gather. GEMM = LDS-resident W + padded-A tile, 4x4 reg
// blocking, pure ds_read_b128 + FMA inner loop.
// ---------------------------------------------------------------------------

__device__ __forceinline__ float lrelu02(float x) {
  return x > 0.f ? x : 0.2f * x;
}

// --- edge dtype detection: int64 (little-endian) has all-odd words == 0 -----
__global__ void detect_kernel(const unsigned* __restrict__ ei, int* __restrict__ flag) {
  int is64 = 1;
  for (int i = 1; i < 128; i += 2) {
    if (ei[i] != 0u) { is64 = 0; break; }
  }
  *flag = is64;
}

// --- convert edge_index -> int32 src/dst (+self loops), histogram degrees ---
__global__ void convert_kernel(const void* __restrict__ ei, int E, int Etot,
                               const int* __restrict__ flag,
                               int* __restrict__ src32, int* __restrict__ dst32,
                               int* __restrict__ deg) {
  int e = blockIdx.x * blockDim.x + threadIdx.x;
  if (e >= Etot) return;
  int s, d;
  if (e < E) {
    if (*flag) {
      const long long* p = (const long long*)ei;
      s = (int)p[e];
      d = (int)p[(size_t)E + e];
    } else {
      const int* p = (const int*)ei;
      s = p[e];
      d = p[E + e];
    }
  } else {  // self loop
    s = d = e - E;
  }
  src32[e] = s;
  dst32[e] = d;
  atomicAdd(&deg[d], 1);
}

// --- single-block exclusive scan of degrees -> row_ptr, cursor --------------
__global__ void scan_kernel(const int* __restrict__ deg, int* __restrict__ row_ptr,
                            int* __restrict__ cursor, int n) {
  __shared__ int sums[1024];
  int tid = threadIdx.x;
  int chunk = (n + 1023) / 1024;
  int lo = tid * chunk;
  int hi = lo + chunk; if (hi > n) hi = n;
  if (lo > n) lo = n;
  int s = 0;
  for (int i = lo; i < hi; ++i) s += deg[i];
  sums[tid] = s;
  __syncthreads();
  for (int off = 1; off < 1024; off <<= 1) {
    int v = (tid >= off) ? sums[tid - off] : 0;
    __syncthreads();
    sums[tid] += v;
    __syncthreads();
  }
  int run = (tid == 0) ? 0 : sums[tid - 1];
  for (int i = lo; i < hi; ++i) {
    row_ptr[i] = run;
    cursor[i] = run;
    run += deg[i];
  }
  if (tid == 1023) row_ptr[n] = sums[1023];
}

// --- scatter edges into CSR (order within a node irrelevant) ----------------
__global__ void scatter_kernel(const int* __restrict__ src32, const int* __restrict__ dst32,
                               int* __restrict__ cursor, int* __restrict__ csr_src, int Etot) {
  int e = blockIdx.x * blockDim.x + threadIdx.x;
  if (e >= Etot) return;
  int d = dst32[e];
  int pos = atomicAdd(&cursor[d], 1);
  csr_src[pos] = src32[e];
}

// --- LDS-resident GEMM: A[n,128] @ W[128,OUTC] -> H[n,OUTC] -----------------
// Block computes BROWS x BCOLS. A tile staged padded (AP=132) to kill bank
// conflicts; W slab staged in natural [k][c] layout (no transpose needed).
// Thread tile TR x 4. 256 threads.
template <int BROWS, int BCOLS, int TR>
__global__ __launch_bounds__(256) void gemm_lds_kernel(const float* __restrict__ A,
                                                       const float* __restrict__ W,
                                                       float* __restrict__ Hout,
                                                       int n, int OUTC) {
  constexpr int TC = 4;
  constexpr int CG = BCOLS / TC;   // col groups
  constexpr int RG = BROWS / TR;   // row groups
  static_assert(CG * RG == 256, "256 threads");
  constexpr int AP = 132;          // padded A row stride (floats)

  __shared__ __align__(16) float A_lds[BROWS * AP];
  __shared__ __align__(16) float W_lds[128 * BCOLS];

  const int r0 = blockIdx.x * BROWS;
  const int cb = blockIdx.y * BCOLS;
  const int t = threadIdx.x;

  // stage A tile (BROWS x 128 floats), guarded rows read as zero
#pragma unroll
  for (int i = 0; i < BROWS / 8; ++i) {
    int slot = t + i * 256;
    int r = slot >> 5;        // row within tile
    int kq = slot & 31;       // float4 index along k
    float4 v = make_float4(0.f, 0.f, 0.f, 0.f);
    if (r0 + r < n) v = *(const float4*)(A + (size_t)(r0 + r) * 128 + kq * 4);
    *(float4*)&A_lds[r * AP + kq * 4] = v;
  }
  // stage W slab (128 x BCOLS floats)
#pragma unroll
  for (int i = 0; i < BCOLS / 8; ++i) {
    int slot = t + i * 256;
    int k = slot / (BCOLS / 4);
    int cq = slot % (BCOLS / 4);
    float4 v = *(const float4*)(W + (size_t)k * OUTC + cb + cq * 4);
    *(float4*)&W_lds[k * BCOLS + cq * 4] = v;
  }
  __syncthreads();

  const int cg = t % CG;
  const int rg = t / CG;

  float acc[TR][TC];
#pragma unroll
  for (int i = 0; i < TR; ++i)
#pragma unroll
    for (int j = 0; j < TC; ++j) acc[i][j] = 0.f;

  for (int k4 = 0; k4 < 32; ++k4) {
    float av[TR][4];
#pragma unroll
    for (int i = 0; i < TR; ++i) {
      float4 a4 = *(const float4*)&A_lds[(rg * TR + i) * AP + k4 * 4];
      av[i][0] = a4.x; av[i][1] = a4.y; av[i][2] = a4.z; av[i][3] = a4.w;
    }
#pragma unroll
    for (int kk = 0; kk < 4; ++kk) {
      float4 w4 = *(const float4*)&W_lds[(k4 * 4 + kk) * BCOLS + cg * TC];
#pragma unroll
      for (int i = 0; i < TR; ++i) {
        acc[i][0] = fmaf(av[i][kk], w4.x, acc[i][0]);
        acc[i][1] = fmaf(av[i][kk], w4.y, acc[i][1]);
        acc[i][2] = fmaf(av[i][kk], w4.z, acc[i][2]);
        acc[i][3] = fmaf(av[i][kk], w4.w, acc[i][3]);
      }
    }
  }

#pragma unroll
  for (int i = 0; i < TR; ++i) {
    int r = r0 + rg * TR + i;
    if (r >= n) continue;
    float4 o = make_float4(acc[i][0], acc[i][1], acc[i][2], acc[i][3]);
    *(float4*)(Hout + (size_t)r * OUTC + cb + cg * TC) = o;
  }
}

// --- attention logits: al[n,h] = sum_c h[n,h,c] * a[h,c] --------------------
template <int H, int C>
__global__ void al_kernel(const float* __restrict__ h, const float* __restrict__ a_s,
                          const float* __restrict__ a_d, float* __restrict__ alS,
                          float* __restrict__ alD, int n) {
  int idx = blockIdx.x * blockDim.x + threadIdx.x;
  if (idx >= n * H) return;
  int head = idx % H;
  const float* hp = h + (size_t)idx * C;  // layout [n,H,C]: idx = node*H+head
  const float* sp = a_s + head * C;
  const float* dp = a_d + head * C;
  float s = 0.f, d = 0.f;
#pragma unroll
  for (int i = 0; i < C; i += 4) {
    float4 hv = *(const float4*)(hp + i);
    float4 sv = *(const float4*)(sp + i);
    float4 dv = *(const float4*)(dp + i);
    s = fmaf(hv.x, sv.x, s); s = fmaf(hv.y, sv.y, s);
    s = fmaf(hv.z, sv.z, s); s = fmaf(hv.w, sv.w, s);
    d = fmaf(hv.x, dv.x, d); d = fmaf(hv.y, dv.y, d);
    d = fmaf(hv.z, dv.z, d); d = fmaf(hv.w, dv.w, d);
  }
  alS[idx] = s;
  alD[idx] = d;
}

// --- agg: lane-parallel staging + unrolled channel-parallel gather ----------
// H=4,C=32: 64 lanes per node, lane handles channels 2sl,2sl+1 (head sl>>4).
// H=1,C=32: 32 lanes per node (2 nodes/wave), lane handles channel sl.
template <int H, int C, bool BN>
__global__ __launch_bounds__(256) void agg_kernel(
    const int* __restrict__ row_ptr, const int* __restrict__ csr_src,
    const float* __restrict__ alS, const float* __restrict__ alD,
    const float* __restrict__ hfeat, const float* __restrict__ bias,
    const float* __restrict__ bnw, const float* __restrict__ bnb,
    const float* __restrict__ bnm, const float* __restrict__ bnv,
    float* __restrict__ out, int n) {
  constexpr int HC = H * C;
  constexpr int LPN = (HC >= 128) ? 64 : 32;  // lanes per node
  constexpr int NPB = 256 / LPN;              // node slots per block
  constexpr int KCAP = 96;                    // staged-edge capacity

  __shared__ __align__(16) float sX[NPB][KCAP * H];
  __shared__ int sIdx[NPB][KCAP];

  const int slot = threadIdx.x / LPN;
  const int sl = threadIdx.x % LPN;
  const int v = blockIdx.x * NPB + slot;
  const bool active = v < n;

  int rs = 0, re = 0;
  if (active) { rs = row_ptr[v]; re = row_ptr[v + 1]; }
  const int deg = re - rs;
  const int degS = deg < KCAP ? deg : KCAP;

  float m[H];
#pragma unroll
  for (int h2 = 0; h2 < H; ++h2) m[h2] = -1e30f;

  if constexpr (H == 4) {
    float4 ad4 = make_float4(0.f, 0.f, 0.f, 0.f);
    if (active) ad4 = *(const float4*)(alD + (size_t)v * 4);
    for (int k = sl; k < degS; k += LPN) {
      int s = csr_src[rs + k];
      sIdx[slot][k] = s;
      float4 a4 = *(const float4*)(alS + (size_t)s * 4);
      float x0 = lrelu02(a4.x + ad4.x);
      float x1 = lrelu02(a4.y + ad4.y);
      float x2 = lrelu02(a4.z + ad4.z);
      float x3 = lrelu02(a4.w + ad4.w);
      ((float4*)&sX[slot][0])[k] = make_float4(x0, x1, x2, x3);
      m[0] = fmaxf(m[0], x0); m[1] = fmaxf(m[1], x1);
      m[2] = fmaxf(m[2], x2); m[3] = fmaxf(m[3], x3);
    }
    // overflow edges contribute to max only (recomputed later)
    for (int k = KCAP + sl; k < deg; k += LPN) {
      int s = csr_src[rs + k];
      float4 a4 = *(const float4*)(alS + (size_t)s * 4);
      m[0] = fmaxf(m[0], lrelu02(a4.x + ad4.x));
      m[1] = fmaxf(m[1], lrelu02(a4.y + ad4.y));
      m[2] = fmaxf(m[2], lrelu02(a4.z + ad4.z));
      m[3] = fmaxf(m[3], lrelu02(a4.w + ad4.w));
    }
#pragma unroll
    for (int h2 = 0; h2 < 4; ++h2) {
#pragma unroll
      for (int off = 32; off >= 1; off >>= 1)
        m[h2] = fmaxf(m[h2], __shfl_xor(m[h2], off));
    }
  } else {  // H == 1
    float ad = active ? alD[v] : 0.f;
    for (int k = sl; k < degS; k += LPN) {
      int s = csr_src[rs + k];
      sIdx[slot][k] = s;
      float x = lrelu02(alS[s] + ad);
      sX[slot][k] = x;
      m[0] = fmaxf(m[0], x);
    }
    for (int k = KCAP + sl; k < deg; k += LPN) {
      int s = csr_src[rs + k];
      m[0] = fmaxf(m[0], lrelu02(alS[s] + ad));
    }
#pragma unroll
    for (int off = 16; off >= 1; off >>= 1)
      m[0] = fmaxf(m[0], __shfl_xor(m[0], off));
  }

  __syncthreads();

  if constexpr (H == 4) {
    const int c = 2 * sl;          // channels c, c+1
    const int h = sl >> 4;         // head 0..3
    const float mh = (h == 0) ? m[0] : (h == 1) ? m[1] : (h == 2) ? m[2] : m[3];
    float2 acc = make_float2(0.f, 0.f);
    float den = 0.f;
    int j = 0;
    for (; j + 4 <= degS; j += 4) {
      int s0 = sIdx[slot][j + 0], s1 = sIdx[slot][j + 1];
      int s2 = sIdx[slot][j + 2], s3 = sIdx[slot][j + 3];
      float x0 = sX[slot][(j + 0) * 4 + h];
      float x1 = sX[slot][(j + 1) * 4 + h];
      float x2 = sX[slot][(j + 2) * 4 + h];
      float x3 = sX[slot][(j + 3) * 4 + h];
      float2 f0 = *(const float2*)(hfeat + (size_t)s0 * 128 + c);
      float2 f1 = *(const float2*)(hfeat + (size_t)s1 * 128 + c);
      float2 f2 = *(const float2*)(hfeat + (size_t)s2 * 128 + c);
      float2 f3 = *(const float2*)(hfeat + (size_t)s3 * 128 + c);
      float w0 = __expf(x0 - mh), w1 = __expf(x1 - mh);
      float w2 = __expf(x2 - mh), w3 = __expf(x3 - mh);
      den += (w0 + w1) + (w2 + w3);
      acc.x = fmaf(w0, f0.x, acc.x); acc.y = fmaf(w0, f0.y, acc.y);
      acc.x = fmaf(w1, f1.x, acc.x); acc.y = fmaf(w1, f1.y, acc.y);
      acc.x = fmaf(w2, f2.x, acc.x); acc.y = fmaf(w2, f2.y, acc.y);
      acc.x = fmaf(w3, f3.x, acc.x); acc.y = fmaf(w3, f3.y, acc.y);
    }
    for (; j < degS; ++j) {
      int s = sIdx[slot][j];
      float x = sX[slot][j * 4 + h];
      float2 f = *(const float2*)(hfeat + (size_t)s * 128 + c);
      float w = __expf(x - mh);
      den += w;
      acc.x = fmaf(w, f.x, acc.x); acc.y = fmaf(w, f.y, acc.y);
    }
    if (deg > KCAP) {  // cold fallback, recompute logits
      float adh = alD[(size_t)v * 4 + h];
      for (int e = rs + KCAP; e < re; ++e) {
        int s = csr_src[e];
        float x = lrelu02(alS[(size_t)s * 4 + h] + adh);
        float w = __expf(x - mh);
        den += w;
        float2 f = *(const float2*)(hfeat + (size_t)s * 128 + c);
        acc.x = fmaf(w, f.x, acc.x); acc.y = fmaf(w, f.y, acc.y);
      }
    }
    if (active) {
      float inv = 1.f / (den + 1e-16f);
      float2 b2v = *(const float2*)(bias + c);
      float g0 = acc.x * inv + b2v.x;
      float g1 = acc.y * inv + b2v.y;
      if constexpr (BN) {
        float2 bw = *(const float2*)(bnw + c);
        float2 bb = *(const float2*)(bnb + c);
        float2 bm = *(const float2*)(bnm + c);
        float2 bv = *(const float2*)(bnv + c);
        g0 = (g0 - bm.x) * (bw.x * rsqrtf(bv.x + 1e-5f)) + bb.x;
        g1 = (g1 - bm.y) * (bw.y * rsqrtf(bv.y + 1e-5f)) + bb.y;
        g0 = fmaxf(g0, 0.f);
        g1 = fmaxf(g1, 0.f);
      }
      *(float2*)(out + (size_t)v * 128 + c) = make_float2(g0, g1);
    }
  } else {  // H == 1, C == 32
    const int c = sl;
    const float mh = m[0];
    float acc = 0.f, den = 0.f;
    int j = 0;
    for (; j + 4 <= degS; j += 4) {
      int s0 = sIdx[slot][j + 0], s1 = sIdx[slot][j + 1];
      int s2 = sIdx[slot][j + 2], s3 = sIdx[slot][j + 3];
      float x0 = sX[slot][j + 0], x1 = sX[slot][j + 1];
      float x2 = sX[slot][j + 2], x3 = sX[slot][j + 3];
      float f0 = hfeat[(size_t)s0 * 32 + c];
      float f1 = hfeat[(size_t)s1 * 32 + c];
      float f2 = hfeat[(size_t)s2 * 32 + c];
      float f3 = hfeat[(size_t)s3 * 32 + c];
      float w0 = __expf(x0 - mh), w1 = __expf(x1 - mh);
      float w2 = __expf(x2 - mh), w3 = __expf(x3 - mh);
      den += (w0 + w1) + (w2 + w3);
      acc = fmaf(w0, f0, acc); acc = fmaf(w1, f1, acc);
      acc = fmaf(w2, f2, acc); acc = fmaf(w3, f3, acc);
    }
    for (; j < degS; ++j) {
      int s = sIdx[slot][j];
      float w = __expf(sX[slot][j] - mh);
      den += w;
      acc = fmaf(w, hfeat[(size_t)s * 32 + c], acc);
    }
    if (deg > KCAP) {
      float ad = alD[v];
      for (int e = rs + KCAP; e < re; ++e) {
        int s = csr_src[e];
        float w = __expf(lrelu02(alS[s] + ad) - mh);
        den += w;
        acc = fmaf(w, hfeat[(size_t)s * 32 + c], acc);
      }
    }
    if (active) {
      out[(size_t)v * 32 + c] = acc / (den + 1e-16f) + bias[c];
    }
  }
}

// ---------------------------------------------------------------------------
extern "C" void kernel_launch(void* const* d_in, const int* in_sizes, int n_in,
                              void* d_out, int out_size, void* d_ws, size_t ws_size,
                              hipStream_t stream) {
  const float* x = (const float*)d_in[0];
  const void* ei = d_in[1];
  const float* w1 = (const float*)d_in[2];
  const float* as1 = (const float*)d_in[3];
  const float* ad1 = (const float*)d_in[4];
  const float* b1 = (const float*)d_in[5];
  const float* bn1w = (const float*)d_in[6];
  const float* bn1b = (const float*)d_in[7];
  const float* bn1m = (const float*)d_in[8];
  const float* bn1v = (const float*)d_in[9];
  const float* w2 = (const float*)d_in[10];
  const float* as2 = (const float*)d_in[11];
  const float* ad2 = (const float*)d_in[12];
  const float* b2 = (const float*)d_in[13];
  const float* bn2w = (const float*)d_in[14];
  const float* bn2b = (const float*)d_in[15];
  const float* bn2m = (const float*)d_in[16];
  const float* bn2v = (const float*)d_in[17];
  const float* w3 = (const float*)d_in[18];
  const float* as3 = (const float*)d_in[19];
  const float* ad3 = (const float*)d_in[20];
  const float* b3 = (const float*)d_in[21];

  const int N = in_sizes[0] / 128;
  const int E = in_sizes[1] / 2;
  const int Etot = E + N;

  // workspace layout (256B aligned slices)
  char* base = (char*)d_ws;
  size_t off = 0;
  auto alloc = [&](size_t bytes) {
    void* p = base + off;
    off = (off + bytes + 255) & ~(size_t)255;
    return p;
  };
  int* flag = (int*)alloc(4);
  int* src32 = (int*)alloc((size_t)Etot * 4);
  int* dst32 = (int*)alloc((size_t)Etot * 4);
  int* deg = (int*)alloc((size_t)N * 4);
  int* row_ptr = (int*)alloc((size_t)(N + 1) * 4);
  int* cursor = (int*)alloc((size_t)N * 4);
  int* csr_src = (int*)alloc((size_t)Etot * 4);
  float* hbuf = (float*)alloc((size_t)N * 128 * 4);
  float* gbuf = (float*)alloc((size_t)N * 128 * 4);
  float* alS = (float*)alloc((size_t)N * 4 * 4);
  float* alD = (float*)alloc((size_t)N * 4 * 4);
  (void)ws_size;

  hipMemsetAsync(deg, 0, (size_t)N * 4, stream);

  detect_kernel<<<1, 1, 0, stream>>>((const unsigned*)ei, flag);
  convert_kernel<<<(Etot + 255) / 256, 256, 0, stream>>>(ei, E, Etot, flag, src32, dst32, deg);
  scan_kernel<<<1, 1024, 0, stream>>>(deg, row_ptr, cursor, N);
  scatter_kernel<<<(Etot + 255) / 256, 256, 0, stream>>>(src32, dst32, cursor, csr_src, Etot);

  const int rowBlocks = (N + 63) / 64;

  // ---- layer 1 ----
  gemm_lds_kernel<64, 64, 4><<<dim3(rowBlocks, 2), 256, 0, stream>>>(x, w1, hbuf, N, 128);
  al_kernel<4, 32><<<(N * 4 + 255) / 256, 256, 0, stream>>>(hbuf, as1, ad1, alS, alD, N);
  agg_kernel<4, 32, true><<<(N + 3) / 4, 256, 0, stream>>>(row_ptr, csr_src, alS, alD, hbuf,
                                                           b1, bn1w, bn1b, bn1m, bn1v, gbuf, N);
  // ---- layer 2 ----
  gemm_lds_kernel<64, 64, 4><<<dim3(rowBlocks, 2), 256, 0, stream>>>(gbuf, w2, hbuf, N, 128);
  al_kernel<4, 32><<<(N * 4 + 255) / 256, 256, 0, stream>>>(hbuf, as2, ad2, alS, alD, N);
  agg_kernel<4, 32, true><<<(N + 3) / 4, 256, 0, stream>>>(row_ptr, csr_src, alS, alD, hbuf,
                                                           b2, bn2w, bn2b, bn2m, bn2v, gbuf, N);
  // ---- layer 3 ----
  gemm_lds_kernel<64, 32, 2><<<dim3(rowBlocks, 1), 256, 0, stream>>>(gbuf, w3, hbuf, N, 32);
  al_kernel<1, 32><<<(N + 255) / 256, 256, 0, stream>>>(hbuf, as3, ad3, alS, alD, N);
  agg_kernel<1, 32, false><<<(N + 7) / 8, 256, 0, stream>>>(row_ptr, csr_src, alS, alD, hbuf,
                                                            b3, nullptr, nullptr, nullptr, nullptr,
                                                            (float*)d_out, N);
}

// Round 4
// 356.410 us; speedup vs baseline: 2.8849x; 1.2960x over previous
//
#include <hip/hip_runtime.h>
#include <hip/hip_bf16.h>
#include <cstdint>

// ---------------------------------------------------------------------------
// EpilepsyGNN: 3-layer GAT (4 heads x 32 -> 4x32 -> 1x32), BN(eval)+ReLU
// CSR by dst built once (multi-block 3-phase scan); agg = lane-parallel LDS
// staging + unrolled channel-parallel gather. GEMM = LDS-resident W + padded
// A tile, 4x4 reg blocking.
// ---------------------------------------------------------------------------

__device__ __forceinline__ float lrelu02(float x) {
  return x > 0.f ? x : 0.2f * x;
}

// --- edge dtype detection: int64 (little-endian) has all-odd words == 0 -----
__global__ void detect_kernel(const unsigned* __restrict__ ei, int* __restrict__ flag) {
  int lane = threadIdx.x;                 // one wave
  unsigned w = ei[2 * lane + 1];          // odd words 1,3,...,127
  unsigned long long nz = __ballot(w != 0u);
  if (lane == 0) *flag = (nz == 0ull) ? 1 : 0;
}

// --- convert edge_index -> int32 src/dst (+self loops), histogram degrees ---
__global__ void convert_kernel(const void* __restrict__ ei, int E, int Etot,
                               const int* __restrict__ flag,
                               int* __restrict__ src32, int* __restrict__ dst32,
                               int* __restrict__ deg) {
  int e = blockIdx.x * blockDim.x + threadIdx.x;
  if (e >= Etot) return;
  int s, d;
  if (e < E) {
    if (*flag) {
      const long long* p = (const long long*)ei;
      s = (int)p[e];
      d = (int)p[(size_t)E + e];
    } else {
      const int* p = (const int*)ei;
      s = p[e];
      d = p[E + e];
    }
  } else {  // self loop
    s = d = e - E;
  }
  src32[e] = s;
  dst32[e] = d;
  atomicAdd(&deg[d], 1);
}

// --- 3-phase device-wide exclusive scan of deg[n] -> row_ptr[n+1], cursor ---
// Phase A: per-block (1024 elems) sums.
__global__ __launch_bounds__(256) void scanA_kernel(const int* __restrict__ deg,
                                                    int* __restrict__ bsum, int n) {
  int t = threadIdx.x;
  int base = blockIdx.x * 1024 + t * 4;
  int s = 0;
#pragma unroll
  for (int j = 0; j < 4; ++j) {
    int i = base + j;
    if (i < n) s += deg[i];
  }
#pragma unroll
  for (int off = 32; off >= 1; off >>= 1) s += __shfl_xor(s, off);
  __shared__ int ws[4];
  int lane = t & 63, wid = t >> 6;
  if (lane == 0) ws[wid] = s;
  __syncthreads();
  if (t == 0) bsum[blockIdx.x] = ws[0] + ws[1] + ws[2] + ws[3];
}

// Phase B: single wave exclusive-scans nb block sums in place; bsum[nb]=total.
__global__ void scanB_kernel(int* __restrict__ bsum, int nb) {
  int lane = threadIdx.x;  // 64 threads
  int carry = 0;
  for (int start = 0; start < nb; start += 64) {
    int i = start + lane;
    int v = (i < nb) ? bsum[i] : 0;
    int inc = v;
#pragma unroll
    for (int off = 1; off < 64; off <<= 1) {
      int u = __shfl_up(inc, off);
      if (lane >= off) inc += u;
    }
    if (i < nb) bsum[i] = inc - v + carry;
    carry += __shfl(inc, 63);
  }
  if (lane == 0) bsum[nb] = carry;
}

// Phase C: per-block exclusive scan + block offset -> row_ptr, cursor.
__global__ __launch_bounds__(256) void scanC_kernel(const int* __restrict__ deg,
                                                    const int* __restrict__ bsum,
                                                    int* __restrict__ row_ptr,
                                                    int* __restrict__ cursor,
                                                    int n, int nb) {
  int t = threadIdx.x;
  int lane = t & 63, wid = t >> 6;
  int base = blockIdx.x * 1024 + t * 4;
  int v[4];
  int ts = 0;
#pragma unroll
  for (int j = 0; j < 4; ++j) {
    int i = base + j;
    v[j] = (i < n) ? deg[i] : 0;
    ts += v[j];
  }
  int inc = ts;
#pragma unroll
  for (int off = 1; off < 64; off <<= 1) {
    int u = __shfl_up(inc, off);
    if (lane >= off) inc += u;
  }
  int wexc = inc - ts;
  __shared__ int wtot[4];
  if (lane == 63) wtot[wid] = inc;
  __syncthreads();
  int wbase = 0;
  for (int w = 0; w < wid; ++w) wbase += wtot[w];
  int run = bsum[blockIdx.x] + wbase + wexc;
#pragma unroll
  for (int j = 0; j < 4; ++j) {
    int i = base + j;
    if (i < n) {
      row_ptr[i] = run;
      cursor[i] = run;
      run += v[j];
    }
  }
  if (blockIdx.x == 0 && t == 0) row_ptr[n] = bsum[nb];
}

// --- scatter edges into CSR (order within a node irrelevant) ----------------
__global__ void scatter_kernel(const int* __restrict__ src32, const int* __restrict__ dst32,
                               int* __restrict__ cursor, int* __restrict__ csr_src, int Etot) {
  int e = blockIdx.x * blockDim.x + threadIdx.x;
  if (e >= Etot) return;
  int d = dst32[e];
  int pos = atomicAdd(&cursor[d], 1);
  csr_src[pos] = src32[e];
}

// --- LDS-resident GEMM: A[n,128] @ W[128,OUTC] -> H[n,OUTC] -----------------
template <int BROWS, int BCOLS, int TR>
__global__ __launch_bounds__(256) void gemm_lds_kernel(const float* __restrict__ A,
                                                       const float* __restrict__ W,
                                                       float* __restrict__ Hout,
                                                       int n, int OUTC) {
  constexpr int TC = 4;
  constexpr int CG = BCOLS / TC;   // col groups
  constexpr int RG = BROWS / TR;   // row groups
  static_assert(CG * RG == 256, "256 threads");
  constexpr int AP = 132;          // padded A row stride (floats)

  __shared__ __align__(16) float A_lds[BROWS * AP];
  __shared__ __align__(16) float W_lds[128 * BCOLS];

  const int r0 = blockIdx.x * BROWS;
  const int cb = blockIdx.y * BCOLS;
  const int t = threadIdx.x;

  // stage A tile (BROWS x 128 floats), guarded rows read as zero
#pragma unroll
  for (int i = 0; i < BROWS / 8; ++i) {
    int slot = t + i * 256;
    int r = slot >> 5;        // row within tile
    int kq = slot & 31;       // float4 index along k
    float4 v = make_float4(0.f, 0.f, 0.f, 0.f);
    if (r0 + r < n) v = *(const float4*)(A + (size_t)(r0 + r) * 128 + kq * 4);
    *(float4*)&A_lds[r * AP + kq * 4] = v;
  }
  // stage W slab (128 x BCOLS floats)
#pragma unroll
  for (int i = 0; i < BCOLS / 8; ++i) {
    int slot = t + i * 256;
    int k = slot / (BCOLS / 4);
    int cq = slot % (BCOLS / 4);
    float4 v = *(const float4*)(W + (size_t)k * OUTC + cb + cq * 4);
    *(float4*)&W_lds[k * BCOLS + cq * 4] = v;
  }
  __syncthreads();

  const int cg = t % CG;
  const int rg = t / CG;

  float acc[TR][TC];
#pragma unroll
  for (int i = 0; i < TR; ++i)
#pragma unroll
    for (int j = 0; j < TC; ++j) acc[i][j] = 0.f;

  for (int k4 = 0; k4 < 32; ++k4) {
    float av[TR][4];
#pragma unroll
    for (int i = 0; i < TR; ++i) {
      float4 a4 = *(const float4*)&A_lds[(rg * TR + i) * AP + k4 * 4];
      av[i][0] = a4.x; av[i][1] = a4.y; av[i][2] = a4.z; av[i][3] = a4.w;
    }
#pragma unroll
    for (int kk = 0; kk < 4; ++kk) {
      float4 w4 = *(const float4*)&W_lds[(k4 * 4 + kk) * BCOLS + cg * TC];
#pragma unroll
      for (int i = 0; i < TR; ++i) {
        acc[i][0] = fmaf(av[i][kk], w4.x, acc[i][0]);
        acc[i][1] = fmaf(av[i][kk], w4.y, acc[i][1]);
        acc[i][2] = fmaf(av[i][kk], w4.z, acc[i][2]);
        acc[i][3] = fmaf(av[i][kk], w4.w, acc[i][3]);
      }
    }
  }

#pragma unroll
  for (int i = 0; i < TR; ++i) {
    int r = r0 + rg * TR + i;
    if (r >= n) continue;
    float4 o = make_float4(acc[i][0], acc[i][1], acc[i][2], acc[i][3]);
    *(float4*)(Hout + (size_t)r * OUTC + cb + cg * TC) = o;
  }
}

// --- attention logits: al[n,h] = sum_c h[n,h,c] * a[h,c] --------------------
template <int H, int C>
__global__ void al_kernel(const float* __restrict__ h, const float* __restrict__ a_s,
                          const float* __restrict__ a_d, float* __restrict__ alS,
                          float* __restrict__ alD, int n) {
  int idx = blockIdx.x * blockDim.x + threadIdx.x;
  if (idx >= n * H) return;
  int head = idx % H;
  const float* hp = h + (size_t)idx * C;  // layout [n,H,C]: idx = node*H+head
  const float* sp = a_s + head * C;
  const float* dp = a_d + head * C;
  float s = 0.f, d = 0.f;
#pragma unroll
  for (int i = 0; i < C; i += 4) {
    float4 hv = *(const float4*)(hp + i);
    float4 sv = *(const float4*)(sp + i);
    float4 dv = *(const float4*)(dp + i);
    s = fmaf(hv.x, sv.x, s); s = fmaf(hv.y, sv.y, s);
    s = fmaf(hv.z, sv.z, s); s = fmaf(hv.w, sv.w, s);
    d = fmaf(hv.x, dv.x, d); d = fmaf(hv.y, dv.y, d);
    d = fmaf(hv.z, dv.z, d); d = fmaf(hv.w, dv.w, d);
  }
  alS[idx] = s;
  alD[idx] = d;
}

// --- agg: lane-parallel staging + unrolled channel-parallel gather ----------
template <int H, int C, bool BN>
__global__ __launch_bounds__(256) void agg_kernel(
    const int* __restrict__ row_ptr, const int* __restrict__ csr_src,
    const float* __restrict__ alS, const float* __restrict__ alD,
    const float* __restrict__ hfeat, const float* __restrict__ bias,
    const float* __restrict__ bnw, const float* __restrict__ bnb,
    const float* __restrict__ bnm, const float* __restrict__ bnv,
    float* __restrict__ out, int n) {
  constexpr int HC = H * C;
  constexpr int LPN = (HC >= 128) ? 64 : 32;  // lanes per node
  constexpr int NPB = 256 / LPN;              // node slots per block
  constexpr int KCAP = 96;                    // staged-edge capacity

  __shared__ __align__(16) float sX[NPB][KCAP * H];
  __shared__ int sIdx[NPB][KCAP];

  const int slot = threadIdx.x / LPN;
  const int sl = threadIdx.x % LPN;
  const int v = blockIdx.x * NPB + slot;
  const bool active = v < n;

  int rs = 0, re = 0;
  if (active) { rs = row_ptr[v]; re = row_ptr[v + 1]; }
  const int deg = re - rs;
  const int degS = deg < KCAP ? deg : KCAP;

  float m[H];
#pragma unroll
  for (int h2 = 0; h2 < H; ++h2) m[h2] = -1e30f;

  if constexpr (H == 4) {
    float4 ad4 = make_float4(0.f, 0.f, 0.f, 0.f);
    if (active) ad4 = *(const float4*)(alD + (size_t)v * 4);
    for (int k = sl; k < degS; k += LPN) {
      int s = csr_src[rs + k];
      sIdx[slot][k] = s;
      float4 a4 = *(const float4*)(alS + (size_t)s * 4);
      float x0 = lrelu02(a4.x + ad4.x);
      float x1 = lrelu02(a4.y + ad4.y);
      float x2 = lrelu02(a4.z + ad4.z);
      float x3 = lrelu02(a4.w + ad4.w);
      ((float4*)&sX[slot][0])[k] = make_float4(x0, x1, x2, x3);
      m[0] = fmaxf(m[0], x0); m[1] = fmaxf(m[1], x1);
      m[2] = fmaxf(m[2], x2); m[3] = fmaxf(m[3], x3);
    }
    // overflow edges contribute to max only (recomputed later)
    for (int k = KCAP + sl; k < deg; k += LPN) {
      int s = csr_src[rs + k];
      float4 a4 = *(const float4*)(alS + (size_t)s * 4);
      m[0] = fmaxf(m[0], lrelu02(a4.x + ad4.x));
      m[1] = fmaxf(m[1], lrelu02(a4.y + ad4.y));
      m[2] = fmaxf(m[2], lrelu02(a4.z + ad4.z));
      m[3] = fmaxf(m[3], lrelu02(a4.w + ad4.w));
    }
#pragma unroll
    for (int h2 = 0; h2 < 4; ++h2) {
#pragma unroll
      for (int off = 32; off >= 1; off >>= 1)
        m[h2] = fmaxf(m[h2], __shfl_xor(m[h2], off));
    }
  } else {  // H == 1
    float ad = active ? alD[v] : 0.f;
    for (int k = sl; k < degS; k += LPN) {
      int s = csr_src[rs + k];
      sIdx[slot][k] = s;
      float x = lrelu02(alS[s] + ad);
      sX[slot][k] = x;
      m[0] = fmaxf(m[0], x);
    }
    for (int k = KCAP + sl; k < deg; k += LPN) {
      int s = csr_src[rs + k];
      m[0] = fmaxf(m[0], lrelu02(alS[s] + ad));
    }
#pragma unroll
    for (int off = 16; off >= 1; off >>= 1)
      m[0] = fmaxf(m[0], __shfl_xor(m[0], off));
  }

  __syncthreads();

  if constexpr (H == 4) {
    const int c = 2 * sl;          // channels c, c+1
    const int h = sl >> 4;         // head 0..3
    const float mh = (h == 0) ? m[0] : (h == 1) ? m[1] : (h == 2) ? m[2] : m[3];
    float2 acc = make_float2(0.f, 0.f);
    float den = 0.f;
    int j = 0;
    for (; j + 4 <= degS; j += 4) {
      int s0 = sIdx[slot][j + 0], s1 = sIdx[slot][j + 1];
      int s2 = sIdx[slot][j + 2], s3 = sIdx[slot][j + 3];
      float x0 = sX[slot][(j + 0) * 4 + h];
      float x1 = sX[slot][(j + 1) * 4 + h];
      float x2 = sX[slot][(j + 2) * 4 + h];
      float x3 = sX[slot][(j + 3) * 4 + h];
      float2 f0 = *(const float2*)(hfeat + (size_t)s0 * 128 + c);
      float2 f1 = *(const float2*)(hfeat + (size_t)s1 * 128 + c);
      float2 f2 = *(const float2*)(hfeat + (size_t)s2 * 128 + c);
      float2 f3 = *(const float2*)(hfeat + (size_t)s3 * 128 + c);
      float w0 = __expf(x0 - mh), w1 = __expf(x1 - mh);
      float w2 = __expf(x2 - mh), w3 = __expf(x3 - mh);
      den += (w0 + w1) + (w2 + w3);
      acc.x = fmaf(w0, f0.x, acc.x); acc.y = fmaf(w0, f0.y, acc.y);
      acc.x = fmaf(w1, f1.x, acc.x); acc.y = fmaf(w1, f1.y, acc.y);
      acc.x = fmaf(w2, f2.x, acc.x); acc.y = fmaf(w2, f2.y, acc.y);
      acc.x = fmaf(w3, f3.x, acc.x); acc.y = fmaf(w3, f3.y, acc.y);
    }
    for (; j < degS; ++j) {
      int s = sIdx[slot][j];
      float x = sX[slot][j * 4 + h];
      float2 f = *(const float2*)(hfeat + (size_t)s * 128 + c);
      float w = __expf(x - mh);
      den += w;
      acc.x = fmaf(w, f.x, acc.x); acc.y = fmaf(w, f.y, acc.y);
    }
    if (deg > KCAP) {  // cold fallback, recompute logits
      float adh = alD[(size_t)v * 4 + h];
      for (int e = rs + KCAP; e < re; ++e) {
        int s = csr_src[e];
        float x = lrelu02(alS[(size_t)s * 4 + h] + adh);
        float w = __expf(x - mh);
        den += w;
        float2 f = *(const float2*)(hfeat + (size_t)s * 128 + c);
        acc.x = fmaf(w, f.x, acc.x); acc.y = fmaf(w, f.y, acc.y);
      }
    }
    if (active) {
      float inv = 1.f / (den + 1e-16f);
      float2 b2v = *(const float2*)(bias + c);
      float g0 = acc.x * inv + b2v.x;
      float g1 = acc.y * inv + b2v.y;
      if constexpr (BN) {
        float2 bw = *(const float2*)(bnw + c);
        float2 bb = *(const float2*)(bnb + c);
        float2 bm = *(const float2*)(bnm + c);
        float2 bv = *(const float2*)(bnv + c);
        g0 = (g0 - bm.x) * (bw.x * rsqrtf(bv.x + 1e-5f)) + bb.x;
        g1 = (g1 - bm.y) * (bw.y * rsqrtf(bv.y + 1e-5f)) + bb.y;
        g0 = fmaxf(g0, 0.f);
        g1 = fmaxf(g1, 0.f);
      }
      *(float2*)(out + (size_t)v * 128 + c) = make_float2(g0, g1);
    }
  } else {  // H == 1, C == 32
    const int c = sl;
    const float mh = m[0];
    float acc = 0.f, den = 0.f;
    int j = 0;
    for (; j + 4 <= degS; j += 4) {
      int s0 = sIdx[slot][j + 0], s1 = sIdx[slot][j + 1];
      int s2 = sIdx[slot][j + 2], s3 = sIdx[slot][j + 3];
      float x0 = sX[slot][j + 0], x1 = sX[slot][j + 1];
      float x2 = sX[slot][j + 2], x3 = sX[slot][j + 3];
      float f0 = hfeat[(size_t)s0 * 32 + c];
      float f1 = hfeat[(size_t)s1 * 32 + c];
      float f2 = hfeat[(size_t)s2 * 32 + c];
      float f3 = hfeat[(size_t)s3 * 32 + c];
      float w0 = __expf(x0 - mh), w1 = __expf(x1 - mh);
      float w2 = __expf(x2 - mh), w3 = __expf(x3 - mh);
      den += (w0 + w1) + (w2 + w3);
      acc = fmaf(w0, f0, acc); acc = fmaf(w1, f1, acc);
      acc = fmaf(w2, f2, acc); acc = fmaf(w3, f3, acc);
    }
    for (; j < degS; ++j) {
      int s = sIdx[slot][j];
      float w = __expf(sX[slot][j] - mh);
      den += w;
      acc = fmaf(w, hfeat[(size_t)s * 32 + c], acc);
    }
    if (deg > KCAP) {
      float ad = alD[v];
      for (int e = rs + KCAP; e < re; ++e) {
        int s = csr_src[e];
        float w = __expf(lrelu02(alS[s] + ad) - mh);
        den += w;
        acc = fmaf(w, hfeat[(size_t)s * 32 + c], acc);
      }
    }
    if (active) {
      out[(size_t)v * 32 + c] = acc / (den + 1e-16f) + bias[c];
    }
  }
}

// ---------------------------------------------------------------------------
extern "C" void kernel_launch(void* const* d_in, const int* in_sizes, int n_in,
                              void* d_out, int out_size, void* d_ws, size_t ws_size,
                              hipStream_t stream) {
  const float* x = (const float*)d_in[0];
  const void* ei = d_in[1];
  const float* w1 = (const float*)d_in[2];
  const float* as1 = (const float*)d_in[3];
  const float* ad1 = (const float*)d_in[4];
  const float* b1 = (const float*)d_in[5];
  const float* bn1w = (const float*)d_in[6];
  const float* bn1b = (const float*)d_in[7];
  const float* bn1m = (const float*)d_in[8];
  const float* bn1v = (const float*)d_in[9];
  const float* w2 = (const float*)d_in[10];
  const float* as2 = (const float*)d_in[11];
  const float* ad2 = (const float*)d_in[12];
  const float* b2 = (const float*)d_in[13];
  const float* bn2w = (const float*)d_in[14];
  const float* bn2b = (const float*)d_in[15];
  const float* bn2m = (const float*)d_in[16];
  const float* bn2v = (const float*)d_in[17];
  const float* w3 = (const float*)d_in[18];
  const float* as3 = (const float*)d_in[19];
  const float* ad3 = (const float*)d_in[20];
  const float* b3 = (const float*)d_in[21];

  const int N = in_sizes[0] / 128;
  const int E = in_sizes[1] / 2;
  const int Etot = E + N;
  const int nb = (N + 1023) / 1024;

  // workspace layout (256B aligned slices)
  char* base = (char*)d_ws;
  size_t off = 0;
  auto alloc = [&](size_t bytes) {
    void* p = base + off;
    off = (off + bytes + 255) & ~(size_t)255;
    return p;
  };
  int* flag = (int*)alloc(4);
  int* src32 = (int*)alloc((size_t)Etot * 4);
  int* dst32 = (int*)alloc((size_t)Etot * 4);
  int* deg = (int*)alloc((size_t)N * 4);
  int* row_ptr = (int*)alloc((size_t)(N + 1) * 4);
  int* cursor = (int*)alloc((size_t)N * 4);
  int* csr_src = (int*)alloc((size_t)Etot * 4);
  int* bsum = (int*)alloc((size_t)(nb + 1) * 4);
  float* hbuf = (float*)alloc((size_t)N * 128 * 4);
  float* gbuf = (float*)alloc((size_t)N * 128 * 4);
  float* alS = (float*)alloc((size_t)N * 4 * 4);
  float* alD = (float*)alloc((size_t)N * 4 * 4);
  (void)ws_size;

  hipMemsetAsync(deg, 0, (size_t)N * 4, stream);

  detect_kernel<<<1, 64, 0, stream>>>((const unsigned*)ei, flag);
  convert_kernel<<<(Etot + 255) / 256, 256, 0, stream>>>(ei, E, Etot, flag, src32, dst32, deg);
  scanA_kernel<<<nb, 256, 0, stream>>>(deg, bsum, N);
  scanB_kernel<<<1, 64, 0, stream>>>(bsum, nb);
  scanC_kernel<<<nb, 256, 0, stream>>>(deg, bsum, row_ptr, cursor, N, nb);
  scatter_kernel<<<(Etot + 255) / 256, 256, 0, stream>>>(src32, dst32, cursor, csr_src, Etot);

  const int rowBlocks = (N + 63) / 64;

  // ---- layer 1 ----
  gemm_lds_kernel<64, 64, 4><<<dim3(rowBlocks, 2), 256, 0, stream>>>(x, w1, hbuf, N, 128);
  al_kernel<4, 32><<<(N * 4 + 255) / 256, 256, 0, stream>>>(hbuf, as1, ad1, alS, alD, N);
  agg_kernel<4, 32, true><<<(N + 3) / 4, 256, 0, stream>>>(row_ptr, csr_src, alS, alD, hbuf,
                                                           b1, bn1w, bn1b, bn1m, bn1v, gbuf, N);
  // ---- layer 2 ----
  gemm_lds_kernel<64, 64, 4><<<dim3(rowBlocks, 2), 256, 0, stream>>>(gbuf, w2, hbuf, N, 128);
  al_kernel<4, 32><<<(N * 4 + 255) / 256, 256, 0, stream>>>(hbuf, as2, ad2, alS, alD, N);
  agg_kernel<4, 32, true><<<(N + 3) / 4, 256, 0, stream>>>(row_ptr, csr_src, alS, alD, hbuf,
                                                           b2, bn2w, bn2b, bn2m, bn2v, gbuf, N);
  // ---- layer 3 ----
  gemm_lds_kernel<64, 32, 2><<<dim3(rowBlocks, 1), 256, 0, stream>>>(gbuf, w3, hbuf, N, 32);
  al_kernel<1, 32><<<(N + 255) / 256, 256, 0, stream>>>(hbuf, as3, ad3, alS, alD, N);
  agg_kernel<1, 32, false><<<(N + 7) / 8, 256, 0, stream>>>(row_ptr, csr_src, alS, alD, hbuf,
                                                            b3, nullptr, nullptr, nullptr, nullptr,
                                                            (float*)d_out, N);
}

// Round 5
// 290.289 us; speedup vs baseline: 3.5419x; 1.2278x over previous
//
#include <hip/hip_runtime.h>
#include <hip/hip_bf16.h>
#include <hip/hip_fp16.h>
#include <cstdint>

// ---------------------------------------------------------------------------
// EpilepsyGNN: 3-layer GAT (4 heads x 32 -> 4x32 -> 1x32), BN(eval)+ReLU
// CSR by dst built once (3-phase scan). GEMM = LDS-resident, writes h as f16
// and computes attention logits (f32) in its epilogue. agg = lane-parallel
// LDS staging + unrolled channel-parallel f16 gather, f32 math.
// ---------------------------------------------------------------------------

__device__ __forceinline__ float lrelu02(float x) {
  return x > 0.f ? x : 0.2f * x;
}

// --- edge dtype detection: int64 (little-endian) has all-odd words == 0 -----
__global__ void detect_kernel(const unsigned* __restrict__ ei, int* __restrict__ flag) {
  int lane = threadIdx.x;                 // one wave
  unsigned w = ei[2 * lane + 1];          // odd words 1,3,...,127
  unsigned long long nz = __ballot(w != 0u);
  if (lane == 0) *flag = (nz == 0ull) ? 1 : 0;
}

// --- convert edge_index -> int32 src/dst (+self loops), histogram degrees ---
__global__ void convert_kernel(const void* __restrict__ ei, int E, int Etot,
                               const int* __restrict__ flag,
                               int* __restrict__ src32, int* __restrict__ dst32,
                               int* __restrict__ deg) {
  int e = blockIdx.x * blockDim.x + threadIdx.x;
  if (e >= Etot) return;
  int s, d;
  if (e < E) {
    if (*flag) {
      const long long* p = (const long long*)ei;
      s = (int)p[e];
      d = (int)p[(size_t)E + e];
    } else {
      const int* p = (const int*)ei;
      s = p[e];
      d = p[E + e];
    }
  } else {  // self loop
    s = d = e - E;
  }
  src32[e] = s;
  dst32[e] = d;
  atomicAdd(&deg[d], 1);
}

// --- 3-phase device-wide exclusive scan of deg[n] -> row_ptr[n+1], cursor ---
__global__ __launch_bounds__(256) void scanA_kernel(const int* __restrict__ deg,
                                                    int* __restrict__ bsum, int n) {
  int t = threadIdx.x;
  int base = blockIdx.x * 1024 + t * 4;
  int s = 0;
#pragma unroll
  for (int j = 0; j < 4; ++j) {
    int i = base + j;
    if (i < n) s += deg[i];
  }
#pragma unroll
  for (int off = 32; off >= 1; off >>= 1) s += __shfl_xor(s, off);
  __shared__ int ws[4];
  int lane = t & 63, wid = t >> 6;
  if (lane == 0) ws[wid] = s;
  __syncthreads();
  if (t == 0) bsum[blockIdx.x] = ws[0] + ws[1] + ws[2] + ws[3];
}

__global__ void scanB_kernel(int* __restrict__ bsum, int nb) {
  int lane = threadIdx.x;  // 64 threads
  int carry = 0;
  for (int start = 0; start < nb; start += 64) {
    int i = start + lane;
    int v = (i < nb) ? bsum[i] : 0;
    int inc = v;
#pragma unroll
    for (int off = 1; off < 64; off <<= 1) {
      int u = __shfl_up(inc, off);
      if (lane >= off) inc += u;
    }
    if (i < nb) bsum[i] = inc - v + carry;
    carry += __shfl(inc, 63);
  }
  if (lane == 0) bsum[nb] = carry;
}

__global__ __launch_bounds__(256) void scanC_kernel(const int* __restrict__ deg,
                                                    const int* __restrict__ bsum,
                                                    int* __restrict__ row_ptr,
                                                    int* __restrict__ cursor,
                                                    int n, int nb) {
  int t = threadIdx.x;
  int lane = t & 63, wid = t >> 6;
  int base = blockIdx.x * 1024 + t * 4;
  int v[4];
  int ts = 0;
#pragma unroll
  for (int j = 0; j < 4; ++j) {
    int i = base + j;
    v[j] = (i < n) ? deg[i] : 0;
    ts += v[j];
  }
  int inc = ts;
#pragma unroll
  for (int off = 1; off < 64; off <<= 1) {
    int u = __shfl_up(inc, off);
    if (lane >= off) inc += u;
  }
  int wexc = inc - ts;
  __shared__ int wtot[4];
  if (lane == 63) wtot[wid] = inc;
  __syncthreads();
  int wbase = 0;
  for (int w = 0; w < wid; ++w) wbase += wtot[w];
  int run = bsum[blockIdx.x] + wbase + wexc;
#pragma unroll
  for (int j = 0; j < 4; ++j) {
    int i = base + j;
    if (i < n) {
      row_ptr[i] = run;
      cursor[i] = run;
      run += v[j];
    }
  }
  if (blockIdx.x == 0 && t == 0) row_ptr[n] = bsum[nb];
}

// --- scatter edges into CSR (order within a node irrelevant) ----------------
__global__ void scatter_kernel(const int* __restrict__ src32, const int* __restrict__ dst32,
                               int* __restrict__ cursor, int* __restrict__ csr_src, int Etot) {
  int e = blockIdx.x * blockDim.x + threadIdx.x;
  if (e >= Etot) return;
  int d = dst32[e];
  int pos = atomicAdd(&cursor[d], 1);
  csr_src[pos] = src32[e];
}

// --- LDS GEMM + al epilogue: A[n,128]@W[128,OUTC] -> Hout(f16), alS/alD(f32)
// Head layout: OUTC = H*32; head of column c is c>>5.
template <int BROWS, int BCOLS, int TR, int H>
__global__ __launch_bounds__(256) void gemm_al_kernel(const float* __restrict__ A,
                                                      const float* __restrict__ W,
                                                      const float* __restrict__ a_src,
                                                      const float* __restrict__ a_dst,
                                                      __half* __restrict__ Hout,
                                                      float* __restrict__ alS,
                                                      float* __restrict__ alD,
                                                      int n, int OUTC) {
  constexpr int TC = 4;
  constexpr int CG = BCOLS / TC;   // col groups
  constexpr int RG = BROWS / TR;   // row groups
  static_assert(CG * RG == 256, "256 threads");
  constexpr int AP = 132;          // padded A row stride (floats)

  __shared__ __align__(16) float A_lds[BROWS * AP];
  __shared__ __align__(16) float W_lds[128 * BCOLS];

  const int r0 = blockIdx.x * BROWS;
  const int cb = blockIdx.y * BCOLS;
  const int t = threadIdx.x;

  // stage A tile (BROWS x 128 floats), guarded rows read as zero
#pragma unroll
  for (int i = 0; i < BROWS / 8; ++i) {
    int slot = t + i * 256;
    int r = slot >> 5;        // row within tile
    int kq = slot & 31;       // float4 index along k
    float4 v = make_float4(0.f, 0.f, 0.f, 0.f);
    if (r0 + r < n) v = *(const float4*)(A + (size_t)(r0 + r) * 128 + kq * 4);
    *(float4*)&A_lds[r * AP + kq * 4] = v;
  }
  // stage W slab (128 x BCOLS floats)
#pragma unroll
  for (int i = 0; i < BCOLS / 8; ++i) {
    int slot = t + i * 256;
    int k = slot / (BCOLS / 4);
    int cq = slot % (BCOLS / 4);
    float4 v = *(const float4*)(W + (size_t)k * OUTC + cb + cq * 4);
    *(float4*)&W_lds[k * BCOLS + cq * 4] = v;
  }
  __syncthreads();

  const int cg = t % CG;
  const int rg = t / CG;

  float acc[TR][TC];
#pragma unroll
  for (int i = 0; i < TR; ++i)
#pragma unroll
    for (int j = 0; j < TC; ++j) acc[i][j] = 0.f;

  for (int k4 = 0; k4 < 32; ++k4) {
    float av[TR][4];
#pragma unroll
    for (int i = 0; i < TR; ++i) {
      float4 a4 = *(const float4*)&A_lds[(rg * TR + i) * AP + k4 * 4];
      av[i][0] = a4.x; av[i][1] = a4.y; av[i][2] = a4.z; av[i][3] = a4.w;
    }
#pragma unroll
    for (int kk = 0; kk < 4; ++kk) {
      float4 w4 = *(const float4*)&W_lds[(k4 * 4 + kk) * BCOLS + cg * TC];
#pragma unroll
      for (int i = 0; i < TR; ++i) {
        acc[i][0] = fmaf(av[i][kk], w4.x, acc[i][0]);
        acc[i][1] = fmaf(av[i][kk], w4.y, acc[i][1]);
        acc[i][2] = fmaf(av[i][kk], w4.z, acc[i][2]);
        acc[i][3] = fmaf(av[i][kk], w4.w, acc[i][3]);
      }
    }
  }

  // ---- write f16 h ----
#pragma unroll
  for (int i = 0; i < TR; ++i) {
    int r = r0 + rg * TR + i;
    if (r >= n) continue;
    __half2 lo = __floats2half2_rn(acc[i][0], acc[i][1]);
    __half2 hi = __floats2half2_rn(acc[i][2], acc[i][3]);
    uint2 pk;
    pk.x = *(const unsigned*)&lo;
    pk.y = *(const unsigned*)&hi;
    *(uint2*)(Hout + (size_t)r * OUTC + cb + cg * TC) = pk;
  }

  // ---- al epilogue: reduce over the 8 col-group lanes of each head ----
  const int head = (cb + cg * TC) >> 5;   // global head id
  const int cLoc = (cg & 7) * 4;          // channel-within-head of col 0
  float as_c[4], ad_c[4];
#pragma unroll
  for (int j = 0; j < 4; ++j) {
    as_c[j] = a_src[head * 32 + cLoc + j];
    ad_c[j] = a_dst[head * 32 + cLoc + j];
  }
#pragma unroll
  for (int i = 0; i < TR; ++i) {
    float ps = acc[i][0] * as_c[0] + acc[i][1] * as_c[1] +
               acc[i][2] * as_c[2] + acc[i][3] * as_c[3];
    float pd = acc[i][0] * ad_c[0] + acc[i][1] * ad_c[1] +
               acc[i][2] * ad_c[2] + acc[i][3] * ad_c[3];
#pragma unroll
    for (int off = 1; off < 8; off <<= 1) {
      ps += __shfl_xor(ps, off);
      pd += __shfl_xor(pd, off);
    }
    if ((cg & 7) == 0) {
      int r = r0 + rg * TR + i;
      if (r < n) {
        alS[(size_t)r * H + head] = ps;
        alD[(size_t)r * H + head] = pd;
      }
    }
  }
}

// --- agg: lane-parallel staging + unrolled channel-parallel f16 gather ------
template <int H, int C, bool BN>
__global__ __launch_bounds__(256) void agg_kernel(
    const int* __restrict__ row_ptr, const int* __restrict__ csr_src,
    const float* __restrict__ alS, const float* __restrict__ alD,
    const __half* __restrict__ hfeat, const float* __restrict__ bias,
    const float* __restrict__ bnw, const float* __restrict__ bnb,
    const float* __restrict__ bnm, const float* __restrict__ bnv,
    float* __restrict__ out, int n) {
  constexpr int HC = H * C;
  constexpr int LPN = (HC >= 128) ? 64 : 32;  // lanes per node
  constexpr int NPB = 256 / LPN;              // node slots per block
  constexpr int KCAP = 96;                    // staged-edge capacity

  __shared__ __align__(16) float sX[NPB][KCAP * H];
  __shared__ int sIdx[NPB][KCAP];

  const int slot = threadIdx.x / LPN;
  const int sl = threadIdx.x % LPN;
  const int v = blockIdx.x * NPB + slot;
  const bool active = v < n;

  int rs = 0, re = 0;
  if (active) { rs = row_ptr[v]; re = row_ptr[v + 1]; }
  const int deg = re - rs;
  const int degS = deg < KCAP ? deg : KCAP;

  float m[H];
#pragma unroll
  for (int h2 = 0; h2 < H; ++h2) m[h2] = -1e30f;

  if constexpr (H == 4) {
    float4 ad4 = make_float4(0.f, 0.f, 0.f, 0.f);
    if (active) ad4 = *(const float4*)(alD + (size_t)v * 4);
    for (int k = sl; k < degS; k += LPN) {
      int s = csr_src[rs + k];
      sIdx[slot][k] = s;
      float4 a4 = *(const float4*)(alS + (size_t)s * 4);
      float x0 = lrelu02(a4.x + ad4.x);
      float x1 = lrelu02(a4.y + ad4.y);
      float x2 = lrelu02(a4.z + ad4.z);
      float x3 = lrelu02(a4.w + ad4.w);
      ((float4*)&sX[slot][0])[k] = make_float4(x0, x1, x2, x3);
      m[0] = fmaxf(m[0], x0); m[1] = fmaxf(m[1], x1);
      m[2] = fmaxf(m[2], x2); m[3] = fmaxf(m[3], x3);
    }
    for (int k = KCAP + sl; k < deg; k += LPN) {
      int s = csr_src[rs + k];
      float4 a4 = *(const float4*)(alS + (size_t)s * 4);
      m[0] = fmaxf(m[0], lrelu02(a4.x + ad4.x));
      m[1] = fmaxf(m[1], lrelu02(a4.y + ad4.y));
      m[2] = fmaxf(m[2], lrelu02(a4.z + ad4.z));
      m[3] = fmaxf(m[3], lrelu02(a4.w + ad4.w));
    }
#pragma unroll
    for (int h2 = 0; h2 < 4; ++h2) {
#pragma unroll
      for (int off = 32; off >= 1; off >>= 1)
        m[h2] = fmaxf(m[h2], __shfl_xor(m[h2], off));
    }
  } else {  // H == 1
    float ad = active ? alD[v] : 0.f;
    for (int k = sl; k < degS; k += LPN) {
      int s = csr_src[rs + k];
      sIdx[slot][k] = s;
      float x = lrelu02(alS[s] + ad);
      sX[slot][k] = x;
      m[0] = fmaxf(m[0], x);
    }
    for (int k = KCAP + sl; k < deg; k += LPN) {
      int s = csr_src[rs + k];
      m[0] = fmaxf(m[0], lrelu02(alS[s] + ad));
    }
#pragma unroll
    for (int off = 16; off >= 1; off >>= 1)
      m[0] = fmaxf(m[0], __shfl_xor(m[0], off));
  }

  __syncthreads();

  if constexpr (H == 4) {
    const int c = 2 * sl;          // channels c, c+1
    const int h = sl >> 4;         // head 0..3
    const float mh = (h == 0) ? m[0] : (h == 1) ? m[1] : (h == 2) ? m[2] : m[3];
    float2 acc = make_float2(0.f, 0.f);
    float den = 0.f;
    int j = 0;
    for (; j + 4 <= degS; j += 4) {
      int s0 = sIdx[slot][j + 0], s1 = sIdx[slot][j + 1];
      int s2 = sIdx[slot][j + 2], s3 = sIdx[slot][j + 3];
      float x0 = sX[slot][(j + 0) * 4 + h];
      float x1 = sX[slot][(j + 1) * 4 + h];
      float x2 = sX[slot][(j + 2) * 4 + h];
      float x3 = sX[slot][(j + 3) * 4 + h];
      __half2 g0 = *(const __half2*)(hfeat + (size_t)s0 * 128 + c);
      __half2 g1 = *(const __half2*)(hfeat + (size_t)s1 * 128 + c);
      __half2 g2 = *(const __half2*)(hfeat + (size_t)s2 * 128 + c);
      __half2 g3 = *(const __half2*)(hfeat + (size_t)s3 * 128 + c);
      float2 f0 = __half22float2(g0);
      float2 f1 = __half22float2(g1);
      float2 f2 = __half22float2(g2);
      float2 f3 = __half22float2(g3);
      float w0 = __expf(x0 - mh), w1 = __expf(x1 - mh);
      float w2 = __expf(x2 - mh), w3 = __expf(x3 - mh);
      den += (w0 + w1) + (w2 + w3);
      acc.x = fmaf(w0, f0.x, acc.x); acc.y = fmaf(w0, f0.y, acc.y);
      acc.x = fmaf(w1, f1.x, acc.x); acc.y = fmaf(w1, f1.y, acc.y);
      acc.x = fmaf(w2, f2.x, acc.x); acc.y = fmaf(w2, f2.y, acc.y);
      acc.x = fmaf(w3, f3.x, acc.x); acc.y = fmaf(w3, f3.y, acc.y);
    }
    for (; j < degS; ++j) {
      int s = sIdx[slot][j];
      float x = sX[slot][j * 4 + h];
      float2 f = __half22float2(*(const __half2*)(hfeat + (size_t)s * 128 + c));
      float w = __expf(x - mh);
      den += w;
      acc.x = fmaf(w, f.x, acc.x); acc.y = fmaf(w, f.y, acc.y);
    }
    if (deg > KCAP) {  // cold fallback, recompute logits
      float adh = alD[(size_t)v * 4 + h];
      for (int e = rs + KCAP; e < re; ++e) {
        int s = csr_src[e];
        float x = lrelu02(alS[(size_t)s * 4 + h] + adh);
        float w = __expf(x - mh);
        den += w;
        float2 f = __half22float2(*(const __half2*)(hfeat + (size_t)s * 128 + c));
        acc.x = fmaf(w, f.x, acc.x); acc.y = fmaf(w, f.y, acc.y);
      }
    }
    if (active) {
      float inv = 1.f / (den + 1e-16f);
      float2 b2v = *(const float2*)(bias + c);
      float g0 = acc.x * inv + b2v.x;
      float g1 = acc.y * inv + b2v.y;
      if constexpr (BN) {
        float2 bw = *(const float2*)(bnw + c);
        float2 bb = *(const float2*)(bnb + c);
        float2 bm = *(const float2*)(bnm + c);
        float2 bv = *(const float2*)(bnv + c);
        g0 = (g0 - bm.x) * (bw.x * rsqrtf(bv.x + 1e-5f)) + bb.x;
        g1 = (g1 - bm.y) * (bw.y * rsqrtf(bv.y + 1e-5f)) + bb.y;
        g0 = fmaxf(g0, 0.f);
        g1 = fmaxf(g1, 0.f);
      }
      *(float2*)(out + (size_t)v * 128 + c) = make_float2(g0, g1);
    }
  } else {  // H == 1, C == 32
    const int c = sl;
    const float mh = m[0];
    float acc = 0.f, den = 0.f;
    int j = 0;
    for (; j + 4 <= degS; j += 4) {
      int s0 = sIdx[slot][j + 0], s1 = sIdx[slot][j + 1];
      int s2 = sIdx[slot][j + 2], s3 = sIdx[slot][j + 3];
      float x0 = sX[slot][j + 0], x1 = sX[slot][j + 1];
      float x2 = sX[slot][j + 2], x3 = sX[slot][j + 3];
      float f0 = __half2float(hfeat[(size_t)s0 * 32 + c]);
      float f1 = __half2float(hfeat[(size_t)s1 * 32 + c]);
      float f2 = __half2float(hfeat[(size_t)s2 * 32 + c]);
      float f3 = __half2float(hfeat[(size_t)s3 * 32 + c]);
      float w0 = __expf(x0 - mh), w1 = __expf(x1 - mh);
      float w2 = __expf(x2 - mh), w3 = __expf(x3 - mh);
      den += (w0 + w1) + (w2 + w3);
      acc = fmaf(w0, f0, acc); acc = fmaf(w1, f1, acc);
      acc = fmaf(w2, f2, acc); acc = fmaf(w3, f3, acc);
    }
    for (; j < degS; ++j) {
      int s = sIdx[slot][j];
      float w = __expf(sX[slot][j] - mh);
      den += w;
      acc = fmaf(w, __half2float(hfeat[(size_t)s * 32 + c]), acc);
    }
    if (deg > KCAP) {
      float ad = alD[v];
      for (int e = rs + KCAP; e < re; ++e) {
        int s = csr_src[e];
        float w = __expf(lrelu02(alS[s] + ad) - mh);
        den += w;
        acc = fmaf(w, __half2float(hfeat[(size_t)s * 32 + c]), acc);
      }
    }
    if (active) {
      out[(size_t)v * 32 + c] = acc / (den + 1e-16f) + bias[c];
    }
  }
}

// ---------------------------------------------------------------------------
extern "C" void kernel_launch(void* const* d_in, const int* in_sizes, int n_in,
                              void* d_out, int out_size, void* d_ws, size_t ws_size,
                              hipStream_t stream) {
  const float* x = (const float*)d_in[0];
  const void* ei = d_in[1];
  const float* w1 = (const float*)d_in[2];
  const float* as1 = (const float*)d_in[3];
  const float* ad1 = (const float*)d_in[4];
  const float* b1 = (const float*)d_in[5];
  const float* bn1w = (const float*)d_in[6];
  const float* bn1b = (const float*)d_in[7];
  const float* bn1m = (const float*)d_in[8];
  const float* bn1v = (const float*)d_in[9];
  const float* w2 = (const float*)d_in[10];
  const float* as2 = (const float*)d_in[11];
  const float* ad2 = (const float*)d_in[12];
  const float* b2 = (const float*)d_in[13];
  const float* bn2w = (const float*)d_in[14];
  const float* bn2b = (const float*)d_in[15];
  const float* bn2m = (const float*)d_in[16];
  const float* bn2v = (const float*)d_in[17];
  const float* w3 = (const float*)d_in[18];
  const float* as3 = (const float*)d_in[19];
  const float* ad3 = (const float*)d_in[20];
  const float* b3 = (const float*)d_in[21];

  const int N = in_sizes[0] / 128;
  const int E = in_sizes[1] / 2;
  const int Etot = E + N;
  const int nb = (N + 1023) / 1024;

  // workspace layout (256B aligned slices)
  char* base = (char*)d_ws;
  size_t off = 0;
  auto alloc = [&](size_t bytes) {
    void* p = base + off;
    off = (off + bytes + 255) & ~(size_t)255;
    return p;
  };
  int* flag = (int*)alloc(4);
  int* src32 = (int*)alloc((size_t)Etot * 4);
  int* dst32 = (int*)alloc((size_t)Etot * 4);
  int* deg = (int*)alloc((size_t)N * 4);
  int* row_ptr = (int*)alloc((size_t)(N + 1) * 4);
  int* cursor = (int*)alloc((size_t)N * 4);
  int* csr_src = (int*)alloc((size_t)Etot * 4);
  int* bsum = (int*)alloc((size_t)(nb + 1) * 4);
  __half* hbuf = (__half*)alloc((size_t)N * 128 * 2);
  float* gbuf = (float*)alloc((size_t)N * 128 * 4);
  float* alS = (float*)alloc((size_t)N * 4 * 4);
  float* alD = (float*)alloc((size_t)N * 4 * 4);
  (void)ws_size;

  hipMemsetAsync(deg, 0, (size_t)N * 4, stream);

  detect_kernel<<<1, 64, 0, stream>>>((const unsigned*)ei, flag);
  convert_kernel<<<(Etot + 255) / 256, 256, 0, stream>>>(ei, E, Etot, flag, src32, dst32, deg);
  scanA_kernel<<<nb, 256, 0, stream>>>(deg, bsum, N);
  scanB_kernel<<<1, 64, 0, stream>>>(bsum, nb);
  scanC_kernel<<<nb, 256, 0, stream>>>(deg, bsum, row_ptr, cursor, N, nb);
  scatter_kernel<<<(Etot + 255) / 256, 256, 0, stream>>>(src32, dst32, cursor, csr_src, Etot);

  const int rowBlocks = (N + 63) / 64;

  // ---- layer 1 ----
  gemm_al_kernel<64, 64, 4, 4><<<dim3(rowBlocks, 2), 256, 0, stream>>>(
      x, w1, as1, ad1, hbuf, alS, alD, N, 128);
  agg_kernel<4, 32, true><<<(N + 3) / 4, 256, 0, stream>>>(row_ptr, csr_src, alS, alD, hbuf,
                                                           b1, bn1w, bn1b, bn1m, bn1v, gbuf, N);
  // ---- layer 2 ----
  gemm_al_kernel<64, 64, 4, 4><<<dim3(rowBlocks, 2), 256, 0, stream>>>(
      gbuf, w2, as2, ad2, hbuf, alS, alD, N, 128);
  agg_kernel<4, 32, true><<<(N + 3) / 4, 256, 0, stream>>>(row_ptr, csr_src, alS, alD, hbuf,
                                                           b2, bn2w, bn2b, bn2m, bn2v, gbuf, N);
  // ---- layer 3 ----
  gemm_al_kernel<64, 32, 2, 1><<<dim3(rowBlocks, 1), 256, 0, stream>>>(
      gbuf, w3, as3, ad3, hbuf, alS, alD, N, 32);
  agg_kernel<1, 32, false><<<(N + 7) / 8, 256, 0, stream>>>(row_ptr, csr_src, alS, alD, hbuf,
                                                            b3, nullptr, nullptr, nullptr, nullptr,
                                                            (float*)d_out, N);
}